// Round 2
// baseline (8502.179 us; speedup 1.0000x reference)
//
#include <hip/hip_runtime.h>
#include <hip/hip_bf16.h>

typedef unsigned int u32;

#define QKV_STRIDE 12582912u   // elements per q/k/v tensor (512*3*256*32)
#define WS_NEED    100663296ull

// bf16-pair helpers: pair packed in one u32, element0 = low 16 bits
__device__ __forceinline__ float bl(u32 u) { return __uint_as_float(u << 16); }
__device__ __forceinline__ float bh(u32 u) { return __uint_as_float(u & 0xffff0000u); }
__device__ __forceinline__ unsigned short bfbits(float f) {
    __hip_bfloat16 b = __float2bfloat16(f);
    return *(unsigned short*)&b;
}
__device__ __forceinline__ u32 pack2(float f0, float f1) {
    return ((u32)bfbits(f1) << 16) | (u32)bfbits(f0);
}

// ---------------- guard: ws too small -> sentinel 1000 ----------------
__global__ __launch_bounds__(256) void k_fill(float* __restrict__ out, int n)
{
    int i = blockIdx.x * 256 + threadIdx.x;
    if (i < n) out[i] = 1000.0f;
}

// ---------------- K1: window-gather + LayerNorm1 -> h (bf16) ----------------
__global__ __launch_bounds__(256) void k_ln1(const float* __restrict__ x,
                                             const float* __restrict__ g1,
                                             const float* __restrict__ b1,
                                             u32* __restrict__ h)
{
    int t = blockIdx.x * 256 + threadIdx.x;          // token id
    int w = t >> 8, n = t & 255;
    int bb = w >> 8, hb = (w >> 4) & 15, wb = w & 15;
    int d = n >> 6, i = (n >> 3) & 7, j = n & 7;
    long off0 = (long)bb * 96 * 65536 + d * 16384 + (hb * 8 + i) * 128 + (wb * 8 + j);
    float s = 0.f, ss = 0.f;
    for (int c = 0; c < 96; ++c) {
        float v = x[off0 + (long)c * 65536];
        s += v; ss += v * v;
    }
    float mean = s * (1.f / 96.f);
    float var  = ss * (1.f / 96.f) - mean * mean;
    float rstd = rsqrtf(var + 1e-5f);
    u32* hr = h + (long)t * 48;
    for (int c2 = 0; c2 < 48; ++c2) {
        float v0 = x[off0 + (long)(2 * c2) * 65536];      // L1-hot reload
        float v1 = x[off0 + (long)(2 * c2 + 1) * 65536];
        float y0 = (v0 - mean) * rstd * g1[2 * c2]     + b1[2 * c2];
        float y1 = (v1 - mean) * rstd * g1[2 * c2 + 1] + b1[2 * c2 + 1];
        hr[c2] = pack2(y0, y1);
    }
}

// ---------------- K2: QKV GEMM (q,k,v outputs share one h row) ----------------
__global__ __launch_bounds__(256) void k_qkv(const u32* __restrict__ h,
                                             const float* __restrict__ qkvw,
                                             const float* __restrict__ qkvb,
                                             __hip_bfloat16* __restrict__ qkv)
{
    u32 u = blockIdx.x * 256 + threadIdx.x;   // ((w*3+head)*256+n)*32+dd
    int dd = u & 31;
    int n  = (u >> 5) & 255;
    u32 wh = u >> 13;                          // w*3+head
    int head = wh % 3, w = wh / 3;
    int tok = (w << 8) | n;
    const u32* hrow = h + (long)tok * 48;
    int r0 = head * 32 + dd;                   // q row; +96 = k row; +192 = v row
    const float* w0 = qkvw + (long)r0 * 96;
    const float* w1 = qkvw + (long)(96 + r0) * 96;
    const float* w2 = qkvw + (long)(192 + r0) * 96;
    float a0 = qkvb[r0], a1 = qkvb[96 + r0], a2 = qkvb[192 + r0];
    #pragma unroll 8
    for (int c = 0; c < 48; ++c) {
        u32 hu = hrow[c];
        float hx = bl(hu), hy = bh(hu);
        a0 = fmaf(hx, w0[2*c], a0); a0 = fmaf(hy, w0[2*c+1], a0);
        a1 = fmaf(hx, w1[2*c], a1); a1 = fmaf(hy, w1[2*c+1], a1);
        a2 = fmaf(hx, w2[2*c], a2); a2 = fmaf(hy, w2[2*c+1], a2);
    }
    qkv[u]                  = __float2bfloat16(a0 * 0.17677669529663687f); // q pre-scaled
    qkv[QKV_STRIDE + u]     = __float2bfloat16(a1);
    qkv[2 * QKV_STRIDE + u] = __float2bfloat16(a2);
}

// ---------------- K3: window attention (online softmax, 2 rows/thread) ----------------
__global__ __launch_bounds__(128) void k_attn(const __hip_bfloat16* __restrict__ qkv,
                                              const float* __restrict__ btab,
                                              u32* __restrict__ o)
{
    __shared__ u32 ks[256 * 16];   // 256 rows x 32 bf16
    __shared__ u32 vs[256 * 16];
    __shared__ float bs[961];
    int wh = blockIdx.x;           // w*3+head
    int head = wh % 3;
    int w = wh / 3;
    int tid = threadIdx.x;
    const u32* kg = (const u32*)(qkv + QKV_STRIDE)     + (long)wh * 4096;
    const u32* vg = (const u32*)(qkv + 2 * QKV_STRIDE) + (long)wh * 4096;
    for (int idx = tid; idx < 4096; idx += 128) { ks[idx] = kg[idx]; vs[idx] = vg[idx]; }
    for (int idx = tid; idx < 961; idx += 128) bs[idx] = btab[idx * 3 + head];
    __syncthreads();

    int n0 = tid, n1 = tid + 128;
    float q0[32], q1[32], acc0[32], acc1[32];
    const u32* q0p = (const u32*)qkv + (long)wh * 4096 + n0 * 16;
    const u32* q1p = (const u32*)qkv + (long)wh * 4096 + n1 * 16;
    #pragma unroll
    for (int c = 0; c < 16; ++c) {
        u32 a = q0p[c]; q0[2*c] = bl(a); q0[2*c+1] = bh(a);
        u32 b = q1p[c]; q1[2*c] = bl(b); q1[2*c+1] = bh(b);
    }
    #pragma unroll
    for (int d2 = 0; d2 < 32; ++d2) { acc0[d2] = 0.f; acc1[d2] = 0.f; }
    float mx0 = -1e30f, mx1 = -1e30f, l0 = 0.f, l1 = 0.f;
    int pi0 = n0 >> 4, pj0 = n0 & 15, pi1 = n1 >> 4, pj1 = n1 & 15;

    for (int m = 0; m < 256; ++m) {
        const u32* kr = &ks[m * 16];
        float s0 = 0.f, s1 = 0.f;
        #pragma unroll
        for (int c = 0; c < 16; ++c) {
            u32 a = kr[c];
            float x0 = bl(a), x1 = bh(a);
            s0 = fmaf(q0[2*c], x0, s0); s0 = fmaf(q0[2*c+1], x1, s0);
            s1 = fmaf(q1[2*c], x0, s1); s1 = fmaf(q1[2*c+1], x1, s1);
        }
        int pim = m >> 4, pjm = m & 15;
        s0 += bs[(pi0 - pim + 15) * 31 + (pj0 - pjm + 15)];
        s1 += bs[(pi1 - pim + 15) * 31 + (pj1 - pjm + 15)];
        float mn0 = fmaxf(mx0, s0), mn1 = fmaxf(mx1, s1);
        float al0 = __expf(mx0 - mn0), al1 = __expf(mx1 - mn1);
        float p0  = __expf(s0 - mn0),  p1  = __expf(s1 - mn1);
        l0 = l0 * al0 + p0; l1 = l1 * al1 + p1;
        mx0 = mn0; mx1 = mn1;
        const u32* vr = &vs[m * 16];
        #pragma unroll
        for (int c = 0; c < 16; ++c) {
            u32 a = vr[c];
            float x0 = bl(a), x1 = bh(a);
            acc0[2*c]   = fmaf(p0, x0, acc0[2*c]   * al0);
            acc0[2*c+1] = fmaf(p0, x1, acc0[2*c+1] * al0);
            acc1[2*c]   = fmaf(p1, x0, acc1[2*c]   * al1);
            acc1[2*c+1] = fmaf(p1, x1, acc1[2*c+1] * al1);
        }
    }
    float inv0 = 1.f / l0, inv1 = 1.f / l1;
    u32* o0 = o + ((long)(w * 256 + n0) * 96 + head * 32) / 2;
    u32* o1 = o + ((long)(w * 256 + n1) * 96 + head * 32) / 2;
    #pragma unroll
    for (int c = 0; c < 16; ++c) {
        o0[c] = pack2(acc0[2*c] * inv0, acc0[2*c+1] * inv0);
        o1[c] = pack2(acc1[2*c] * inv1, acc1[2*c+1] * inv1);
    }
}

// ---------------- K4a: proj + residual(gathered x) -> t2 (fp32) ----------------
__global__ __launch_bounds__(256) void k_proj(const u32* __restrict__ o,
                                              const float* __restrict__ pw,
                                              const float* __restrict__ pb,
                                              const float* __restrict__ x,
                                              float* __restrict__ t2)
{
    u32 u = blockIdx.x * 256 + threadIdx.x;   // t*96 + c
    int c = u % 96; u32 t = u / 96;
    const u32* orow = o + (long)t * 48;
    const float* wrow = pw + (long)c * 96;
    float a = pb[c];
    #pragma unroll 8
    for (int k = 0; k < 48; ++k) {
        u32 ov = orow[k];
        a = fmaf(bl(ov), wrow[2*k],   a);
        a = fmaf(bh(ov), wrow[2*k+1], a);
    }
    int w = t >> 8, n = t & 255;
    int bb = w >> 8, hb = (w >> 4) & 15, wb = w & 15;
    int d = n >> 6, i = (n >> 3) & 7, j = n & 7;
    long xoff = ((long)bb * 96 + c) * 65536 + d * 16384 + (hb * 8 + i) * 128 + (wb * 8 + j);
    t2[u] = a + x[xoff];
}

// ---------------- K4b: LayerNorm2 -> h2 (bf16) ----------------
__global__ __launch_bounds__(256) void k_ln2(const float* __restrict__ t2,
                                             const float* __restrict__ g2,
                                             const float* __restrict__ b2,
                                             u32* __restrict__ h2)
{
    int t = blockIdx.x * 256 + threadIdx.x;
    const float* r = t2 + (long)t * 96;
    float s = 0.f, ss = 0.f;
    for (int c = 0; c < 96; ++c) {
        float v = r[c];
        s += v; ss += v * v;
    }
    float mean = s * (1.f / 96.f);
    float var  = ss * (1.f / 96.f) - mean * mean;
    float rstd = rsqrtf(var + 1e-5f);
    u32* outr = h2 + (long)t * 48;
    for (int c2 = 0; c2 < 48; ++c2) {
        float y0 = (r[2*c2]     - mean) * rstd * g2[2*c2]     + b2[2*c2];
        float y1 = (r[2*c2 + 1] - mean) * rstd * g2[2*c2 + 1] + b2[2*c2 + 1];
        outr[c2] = pack2(y0, y1);
    }
}

// ---------------- K5: fc1 + exact GELU (4 hidden/thread) ----------------
__global__ __launch_bounds__(256) void k_fc1(const u32* __restrict__ h2,
                                             const float* __restrict__ fw,
                                             const float* __restrict__ fb,
                                             u32* __restrict__ m1, int t0)
{
    u32 u = blockIdx.x * 256 + threadIdx.x;   // tl*96 + hx4  (chunk of 32768 tokens)
    int hx4 = u % 96; u32 tl = u / 96;
    int hx = hx4 * 4;
    const u32* hrow = h2 + ((long)t0 + tl) * 48;
    const float* w0 = fw + (long)(hx + 0) * 96;
    const float* w1 = fw + (long)(hx + 1) * 96;
    const float* w2 = fw + (long)(hx + 2) * 96;
    const float* w3 = fw + (long)(hx + 3) * 96;
    float a0 = fb[hx], a1 = fb[hx+1], a2 = fb[hx+2], a3 = fb[hx+3];
    #pragma unroll 4
    for (int k = 0; k < 48; ++k) {
        u32 hv = hrow[k]; float h0 = bl(hv), h1 = bh(hv);
        a0 = fmaf(h0, w0[2*k], a0); a0 = fmaf(h1, w0[2*k+1], a0);
        a1 = fmaf(h0, w1[2*k], a1); a1 = fmaf(h1, w1[2*k+1], a1);
        a2 = fmaf(h0, w2[2*k], a2); a2 = fmaf(h1, w2[2*k+1], a2);
        a3 = fmaf(h0, w3[2*k], a3); a3 = fmaf(h1, w3[2*k+1], a3);
    }
    const float is2 = 0.70710678118654752440f;
    a0 = 0.5f * a0 * (1.f + erff(a0 * is2));
    a1 = 0.5f * a1 * (1.f + erff(a1 * is2));
    a2 = 0.5f * a2 * (1.f + erff(a2 * is2));
    a3 = 0.5f * a3 * (1.f + erff(a3 * is2));
    u32* mo = m1 + (long)tl * 192 + hx / 2;
    mo[0] = pack2(a0, a1);
    mo[1] = pack2(a2, a3);
}

// ---------------- K6: fc2 + residual -> out (4 ch/thread, fp32 out) ----------------
__global__ __launch_bounds__(256) void k_fc2(const u32* __restrict__ m1,
                                             const float* __restrict__ fw,
                                             const float* __restrict__ fb,
                                             const float* __restrict__ t2,
                                             float* __restrict__ out, int t0)
{
    u32 u = blockIdx.x * 256 + threadIdx.x;   // tl*24 + c4
    int c4 = u % 24; u32 tl = u / 24;
    int c = c4 * 4;
    const u32* mrow = m1 + (long)tl * 192;
    const float* w0 = fw + (long)(c + 0) * 384;
    const float* w1 = fw + (long)(c + 1) * 384;
    const float* w2 = fw + (long)(c + 2) * 384;
    const float* w3 = fw + (long)(c + 3) * 384;
    float a0 = fb[c], a1 = fb[c+1], a2 = fb[c+2], a3 = fb[c+3];
    #pragma unroll 4
    for (int k = 0; k < 192; ++k) {
        u32 mv = mrow[k]; float m0 = bl(mv), m1v = bh(mv);
        a0 = fmaf(m0, w0[2*k], a0); a0 = fmaf(m1v, w0[2*k+1], a0);
        a1 = fmaf(m0, w1[2*k], a1); a1 = fmaf(m1v, w1[2*k+1], a1);
        a2 = fmaf(m0, w2[2*k], a2); a2 = fmaf(m1v, w2[2*k+1], a2);
        a3 = fmaf(m0, w3[2*k], a3); a3 = fmaf(m1v, w3[2*k+1], a3);
    }
    long tg = ((long)t0 + tl) * 96 + c;
    out[tg + 0] = t2[tg + 0] + a0;
    out[tg + 1] = t2[tg + 1] + a1;
    out[tg + 2] = t2[tg + 2] + a2;
    out[tg + 3] = t2[tg + 3] + a3;
}

extern "C" void kernel_launch(void* const* d_in, const int* in_sizes, int n_in,
                              void* d_out, int out_size, void* d_ws, size_t ws_size,
                              hipStream_t stream)
{
    const float* x     = (const float*)d_in[0];
    const float* qkvw  = (const float*)d_in[1];
    const float* qkvb  = (const float*)d_in[2];
    const float* projw = (const float*)d_in[3];
    const float* projb = (const float*)d_in[4];
    const float* btab  = (const float*)d_in[5];
    const float* ln1g  = (const float*)d_in[6];
    const float* ln1b  = (const float*)d_in[7];
    const float* ln2g  = (const float*)d_in[8];
    const float* ln2b  = (const float*)d_in[9];
    const float* fc1w  = (const float*)d_in[10];
    const float* fc1b  = (const float*)d_in[11];
    const float* fc2w  = (const float*)d_in[12];
    const float* fc2b  = (const float*)d_in[13];
    float* out = (float*)d_out;

    if (ws_size < WS_NEED) {                // diagnostic: absmax ~1000 => ws too small
        k_fill<<<49152, 256, 0, stream>>>(out, out_size);
        return;
    }

    // ws layout (96 MiB peak):
    //  A [0, 25165824)          : h(bf16) -> o(bf16) -> m1 chunk(bf16, 32768 tok)
    //  B [25165824, 100663296)  : qkv(bf16, 72 MiB) -> { t2(fp32, 48 MiB) ; h2(bf16, 24 MiB) }
    char* ws = (char*)d_ws;
    u32*            hbuf  = (u32*)(ws);
    __hip_bfloat16* qkvB  = (__hip_bfloat16*)(ws + 25165824);
    u32*            obuf  = hbuf;                       // h dead after k_qkv
    float*          t2buf = (float*)(ws + 25165824);    // qkv dead after k_attn
    u32*            h2buf = (u32*)(ws + 75497472);
    u32*            m1buf = hbuf;                       // o dead after k_proj

    k_ln1 <<<512,   256, 0, stream>>>(x, ln1g, ln1b, hbuf);
    k_qkv <<<49152, 256, 0, stream>>>(hbuf, qkvw, qkvb, qkvB);
    k_attn<<<1536,  128, 0, stream>>>(qkvB, btab, obuf);
    k_proj<<<49152, 256, 0, stream>>>(obuf, projw, projb, x, t2buf);
    k_ln2 <<<512,   256, 0, stream>>>(t2buf, ln2g, ln2b, h2buf);
    for (int ch = 0; ch < 4; ++ch) {
        int t0 = ch * 32768;
        k_fc1<<<12288, 256, 0, stream>>>(h2buf, fc1w, fc1b, m1buf, t0);
        k_fc2<<<3072,  256, 0, stream>>>(m1buf, fc2w, fc2b, t2buf, out, t0);
    }
}

// Round 3
// 968.414 us; speedup vs baseline: 8.7795x; 8.7795x over previous
//
#include <hip/hip_runtime.h>
#include <hip/hip_bf16.h>

typedef unsigned int u32;
using bf16x8 = __attribute__((ext_vector_type(8))) short;
using f32x4  = __attribute__((ext_vector_type(4))) float;

#define QKV_STRIDE 12582912u   // elements per q/k/v tensor (512*3*256*32)
#define WS_NEED    100663296ull

__device__ __forceinline__ float bl(u32 u) { return __uint_as_float(u << 16); }
__device__ __forceinline__ float bh(u32 u) { return __uint_as_float(u & 0xffff0000u); }
__device__ __forceinline__ unsigned short bfbits(float f) {
    __hip_bfloat16 b = __float2bfloat16(f);
    return *(unsigned short*)&b;
}
__device__ __forceinline__ u32 pack2(float f0, float f1) {
    return ((u32)bfbits(f1) << 16) | (u32)bfbits(f0);
}

#define MFMA(a, b, c) __builtin_amdgcn_mfma_f32_16x16x32_bf16(a, b, c, 0, 0, 0)

// ---------------- guard: ws too small -> sentinel 1000 ----------------
__global__ __launch_bounds__(256) void k_fill(float* __restrict__ out, int n)
{
    int i = blockIdx.x * 256 + threadIdx.x;
    if (i < n) out[i] = 1000.0f;
}

// ---------------- K1: window-gather + LayerNorm1 -> h (bf16) [unchanged] ----------------
__global__ __launch_bounds__(256) void k_ln1(const float* __restrict__ x,
                                             const float* __restrict__ g1,
                                             const float* __restrict__ b1,
                                             u32* __restrict__ h)
{
    int t = blockIdx.x * 256 + threadIdx.x;
    int w = t >> 8, n = t & 255;
    int bb = w >> 8, hb = (w >> 4) & 15, wb = w & 15;
    int d = n >> 6, i = (n >> 3) & 7, j = n & 7;
    long off0 = (long)bb * 96 * 65536 + d * 16384 + (hb * 8 + i) * 128 + (wb * 8 + j);
    float s = 0.f, ss = 0.f;
    for (int c = 0; c < 96; ++c) {
        float v = x[off0 + (long)c * 65536];
        s += v; ss += v * v;
    }
    float mean = s * (1.f / 96.f);
    float var  = ss * (1.f / 96.f) - mean * mean;
    float rstd = rsqrtf(var + 1e-5f);
    u32* hr = h + (long)t * 48;
    for (int c2 = 0; c2 < 48; ++c2) {
        float v0 = x[off0 + (long)(2 * c2) * 65536];
        float v1 = x[off0 + (long)(2 * c2 + 1) * 65536];
        float y0 = (v0 - mean) * rstd * g1[2 * c2]     + b1[2 * c2];
        float y1 = (v1 - mean) * rstd * g1[2 * c2 + 1] + b1[2 * c2 + 1];
        hr[c2] = pack2(y0, y1);
    }
}

// ---------------- K2: QKV GEMM via MFMA ----------------
// block = 256 thr = 4 waves; each wave: 4 m-tiles (64 tokens); block = 256 tokens.
__global__ __launch_bounds__(256) void k_qkv_m(const __hip_bfloat16* __restrict__ h,
                                               const float* __restrict__ qkvw,
                                               const float* __restrict__ qkvb,
                                               __hip_bfloat16* __restrict__ qkv)
{
    __shared__ short wsm[288 * 96];                 // 55296 B bf16 weights
    int tid = threadIdx.x;
    for (int idx = tid; idx < 288 * 96; idx += 256) wsm[idx] = (short)bfbits(qkvw[idx]);
    __syncthreads();

    int wave = tid >> 6, lane = tid & 63;
    int quad = lane >> 4, l16 = lane & 15;
    int mbase = blockIdx.x * 256 + wave * 64;

    bf16x8 A[4][3];
    #pragma unroll
    for (int mm = 0; mm < 4; ++mm) {
        const __hip_bfloat16* ap = h + (long)(mbase + mm * 16 + l16) * 96 + quad * 8;
        A[mm][0] = *(const bf16x8*)(ap);
        A[mm][1] = *(const bf16x8*)(ap + 32);
        A[mm][2] = *(const bf16x8*)(ap + 64);
    }

    for (int nt = 0; nt < 18; ++nt) {
        int n0 = nt * 16;
        const short* bp = &wsm[(n0 + l16) * 96 + quad * 8];
        bf16x8 B0 = *(const bf16x8*)(bp);
        bf16x8 B1 = *(const bf16x8*)(bp + 32);
        bf16x8 B2 = *(const bf16x8*)(bp + 64);
        int r    = n0 + l16;                 // output row of qkv_w (0..287)
        int type = n0 / 96;                  // 0=q 1=k 2=v (uniform per n-tile)
        int head = (n0 % 96) / 32;           // uniform per n-tile
        int dd   = r & 31;
        float bias = qkvb[r];
        float scl  = (type == 0) ? 0.17677669529663687f : 1.0f;
        long tbase = (long)type * QKV_STRIDE;
        #pragma unroll
        for (int mm = 0; mm < 4; ++mm) {
            f32x4 acc = {0.f, 0.f, 0.f, 0.f};
            acc = MFMA(A[mm][0], B0, acc);
            acc = MFMA(A[mm][1], B1, acc);
            acc = MFMA(A[mm][2], B2, acc);
            int tok0 = mbase + mm * 16 + quad * 4;
            int w = tok0 >> 8, nn = tok0 & 255;
            long dst0 = tbase + (long)(w * 3 + head) * 8192 + nn * 32 + dd;
            #pragma unroll
            for (int rg = 0; rg < 4; ++rg)
                qkv[dst0 + (long)rg * 32] = __float2bfloat16((acc[rg] + bias) * scl);
        }
    }
}

// ---------------- K3: window attention (scalar, unchanged/known-good) ----------------
__global__ __launch_bounds__(128) void k_attn(const __hip_bfloat16* __restrict__ qkv,
                                              const float* __restrict__ btab,
                                              u32* __restrict__ o)
{
    __shared__ u32 ks[256 * 16];
    __shared__ u32 vs[256 * 16];
    __shared__ float bs[961];
    int wh = blockIdx.x;
    int head = wh % 3;
    int w = wh / 3;
    int tid = threadIdx.x;
    const u32* kg = (const u32*)(qkv + QKV_STRIDE)     + (long)wh * 4096;
    const u32* vg = (const u32*)(qkv + 2 * QKV_STRIDE) + (long)wh * 4096;
    for (int idx = tid; idx < 4096; idx += 128) { ks[idx] = kg[idx]; vs[idx] = vg[idx]; }
    for (int idx = tid; idx < 961; idx += 128) bs[idx] = btab[idx * 3 + head];
    __syncthreads();

    int n0 = tid, n1 = tid + 128;
    float q0[32], q1[32], acc0[32], acc1[32];
    const u32* q0p = (const u32*)qkv + (long)wh * 4096 + n0 * 16;
    const u32* q1p = (const u32*)qkv + (long)wh * 4096 + n1 * 16;
    #pragma unroll
    for (int c = 0; c < 16; ++c) {
        u32 a = q0p[c]; q0[2*c] = bl(a); q0[2*c+1] = bh(a);
        u32 b = q1p[c]; q1[2*c] = bl(b); q1[2*c+1] = bh(b);
    }
    #pragma unroll
    for (int d2 = 0; d2 < 32; ++d2) { acc0[d2] = 0.f; acc1[d2] = 0.f; }
    float mx0 = -1e30f, mx1 = -1e30f, l0 = 0.f, l1 = 0.f;
    int pi0 = n0 >> 4, pj0 = n0 & 15, pi1 = n1 >> 4, pj1 = n1 & 15;

    for (int m = 0; m < 256; ++m) {
        const u32* kr = &ks[m * 16];
        float s0 = 0.f, s1 = 0.f;
        #pragma unroll
        for (int c = 0; c < 16; ++c) {
            u32 a = kr[c];
            float x0 = bl(a), x1 = bh(a);
            s0 = fmaf(q0[2*c], x0, s0); s0 = fmaf(q0[2*c+1], x1, s0);
            s1 = fmaf(q1[2*c], x0, s1); s1 = fmaf(q1[2*c+1], x1, s1);
        }
        int pim = m >> 4, pjm = m & 15;
        s0 += bs[(pi0 - pim + 15) * 31 + (pj0 - pjm + 15)];
        s1 += bs[(pi1 - pim + 15) * 31 + (pj1 - pjm + 15)];
        float mn0 = fmaxf(mx0, s0), mn1 = fmaxf(mx1, s1);
        float al0 = __expf(mx0 - mn0), al1 = __expf(mx1 - mn1);
        float p0  = __expf(s0 - mn0),  p1  = __expf(s1 - mn1);
        l0 = l0 * al0 + p0; l1 = l1 * al1 + p1;
        mx0 = mn0; mx1 = mn1;
        const u32* vr = &vs[m * 16];
        #pragma unroll
        for (int c = 0; c < 16; ++c) {
            u32 a = vr[c];
            float x0 = bl(a), x1 = bh(a);
            acc0[2*c]   = fmaf(p0, x0, acc0[2*c]   * al0);
            acc0[2*c+1] = fmaf(p0, x1, acc0[2*c+1] * al0);
            acc1[2*c]   = fmaf(p1, x0, acc1[2*c]   * al1);
            acc1[2*c+1] = fmaf(p1, x1, acc1[2*c+1] * al1);
        }
    }
    float inv0 = 1.f / l0, inv1 = 1.f / l1;
    u32* o0 = o + ((long)(w * 256 + n0) * 96 + head * 32) / 2;
    u32* o1 = o + ((long)(w * 256 + n1) * 96 + head * 32) / 2;
    #pragma unroll
    for (int c = 0; c < 16; ++c) {
        o0[c] = pack2(acc0[2*c] * inv0, acc0[2*c+1] * inv0);
        o1[c] = pack2(acc1[2*c] * inv1, acc1[2*c+1] * inv1);
    }
}

// ---------------- K4a: proj + residual(gathered x) -> t2 (fp32), MFMA ----------------
__global__ __launch_bounds__(256) void k_proj_m(const __hip_bfloat16* __restrict__ o,
                                                const float* __restrict__ pw,
                                                const float* __restrict__ pb,
                                                const float* __restrict__ x,
                                                float* __restrict__ t2)
{
    __shared__ short wsm[96 * 96];                  // 18432 B
    int tid = threadIdx.x;
    for (int idx = tid; idx < 96 * 96; idx += 256) wsm[idx] = (short)bfbits(pw[idx]);
    __syncthreads();

    int wave = tid >> 6, lane = tid & 63;
    int quad = lane >> 4, l16 = lane & 15;
    int mbase = blockIdx.x * 256 + wave * 64;

    bf16x8 A[4][3];
    #pragma unroll
    for (int mm = 0; mm < 4; ++mm) {
        const __hip_bfloat16* ap = o + (long)(mbase + mm * 16 + l16) * 96 + quad * 8;
        A[mm][0] = *(const bf16x8*)(ap);
        A[mm][1] = *(const bf16x8*)(ap + 32);
        A[mm][2] = *(const bf16x8*)(ap + 64);
    }

    for (int nt = 0; nt < 6; ++nt) {
        int n0 = nt * 16;
        const short* bp = &wsm[(n0 + l16) * 96 + quad * 8];
        bf16x8 B0 = *(const bf16x8*)(bp);
        bf16x8 B1 = *(const bf16x8*)(bp + 32);
        bf16x8 B2 = *(const bf16x8*)(bp + 64);
        int c = n0 + l16;
        float bias = pb[c];
        #pragma unroll
        for (int mm = 0; mm < 4; ++mm) {
            f32x4 acc = {0.f, 0.f, 0.f, 0.f};
            acc = MFMA(A[mm][0], B0, acc);
            acc = MFMA(A[mm][1], B1, acc);
            acc = MFMA(A[mm][2], B2, acc);
            int tok0 = mbase + mm * 16 + quad * 4;
            int w = tok0 >> 8, nn = tok0 & 255;
            int bb = w >> 8, hb = (w >> 4) & 15, wb = w & 15;
            int d = nn >> 6, ii = (nn >> 3) & 7, jj = nn & 7;
            long xoff = ((long)bb * 96 + c) * 65536 + d * 16384 + (hb * 8 + ii) * 128 + wb * 8 + jj;
            f32x4 xv = *(const f32x4*)&x[xoff];      // 4 consecutive tokens, same channel
            #pragma unroll
            for (int rg = 0; rg < 4; ++rg)
                t2[(long)(tok0 + rg) * 96 + c] = acc[rg] + bias + xv[rg];
        }
    }
}

// ---------------- K4b: LayerNorm2 -> h2 (bf16) [unchanged] ----------------
__global__ __launch_bounds__(256) void k_ln2(const float* __restrict__ t2,
                                             const float* __restrict__ g2,
                                             const float* __restrict__ b2,
                                             u32* __restrict__ h2)
{
    int t = blockIdx.x * 256 + threadIdx.x;
    const float* r = t2 + (long)t * 96;
    float s = 0.f, ss = 0.f;
    for (int c = 0; c < 96; ++c) {
        float v = r[c];
        s += v; ss += v * v;
    }
    float mean = s * (1.f / 96.f);
    float var  = ss * (1.f / 96.f) - mean * mean;
    float rstd = rsqrtf(var + 1e-5f);
    u32* outr = h2 + (long)t * 48;
    for (int c2 = 0; c2 < 48; ++c2) {
        float y0 = (r[2*c2]     - mean) * rstd * g2[2*c2]     + b2[2*c2];
        float y1 = (r[2*c2 + 1] - mean) * rstd * g2[2*c2 + 1] + b2[2*c2 + 1];
        outr[c2] = pack2(y0, y1);
    }
}

// ---------------- K5: fc1 + exact GELU via MFMA (2 weight phases) ----------------
// block = 4 waves x 2 m-tiles = 128 tokens of a 32768-token chunk
__global__ __launch_bounds__(256) void k_fc1_m(const __hip_bfloat16* __restrict__ h2,
                                               const float* __restrict__ fw,
                                               const float* __restrict__ fb,
                                               __hip_bfloat16* __restrict__ m1, int t0)
{
    __shared__ short wsm[192 * 96];                 // 36864 B per phase
    int tid = threadIdx.x;
    int wave = tid >> 6, lane = tid & 63;
    int quad = lane >> 4, l16 = lane & 15;
    int mbaseL = blockIdx.x * 128 + wave * 32;      // chunk-local token base

    bf16x8 A[2][3];
    #pragma unroll
    for (int mm = 0; mm < 2; ++mm) {
        const __hip_bfloat16* ap = h2 + (long)(t0 + mbaseL + mm * 16 + l16) * 96 + quad * 8;
        A[mm][0] = *(const bf16x8*)(ap);
        A[mm][1] = *(const bf16x8*)(ap + 32);
        A[mm][2] = *(const bf16x8*)(ap + 64);
    }

    const float is2 = 0.70710678118654752440f;
    for (int ph = 0; ph < 2; ++ph) {
        if (ph) __syncthreads();
        for (int idx = tid; idx < 192 * 96; idx += 256)
            wsm[idx] = (short)bfbits(fw[ph * 192 * 96 + idx]);
        __syncthreads();
        for (int nt = 0; nt < 12; ++nt) {
            int n0 = nt * 16;
            const short* bp = &wsm[(n0 + l16) * 96 + quad * 8];
            bf16x8 B0 = *(const bf16x8*)(bp);
            bf16x8 B1 = *(const bf16x8*)(bp + 32);
            bf16x8 B2 = *(const bf16x8*)(bp + 64);
            int r = ph * 192 + n0 + l16;            // hidden index 0..383
            float bias = fb[r];
            #pragma unroll
            for (int mm = 0; mm < 2; ++mm) {
                f32x4 acc = {0.f, 0.f, 0.f, 0.f};
                acc = MFMA(A[mm][0], B0, acc);
                acc = MFMA(A[mm][1], B1, acc);
                acc = MFMA(A[mm][2], B2, acc);
                int tokL0 = mbaseL + mm * 16 + quad * 4;
                #pragma unroll
                for (int rg = 0; rg < 4; ++rg) {
                    float v = acc[rg] + bias;
                    v = 0.5f * v * (1.f + erff(v * is2));
                    m1[(long)(tokL0 + rg) * 384 + r] = __float2bfloat16(v);
                }
            }
        }
    }
}

// ---------------- K6: fc2 + residual -> out via MFMA (2 weight phases) ----------------
// block = 4 waves x 2 m-tiles = 128 tokens; K=384 (12 chunks); N=96
__global__ __launch_bounds__(256) void k_fc2_m(const __hip_bfloat16* __restrict__ m1,
                                               const float* __restrict__ fw,
                                               const float* __restrict__ fb,
                                               const float* __restrict__ t2,
                                               float* __restrict__ out, int t0)
{
    __shared__ short wsm[48 * 392];                 // 37632 B per phase (K padded 384->392)
    int tid = threadIdx.x;
    int wave = tid >> 6, lane = tid & 63;
    int quad = lane >> 4, l16 = lane & 15;
    int mbaseL = blockIdx.x * 128 + wave * 32;

    bf16x8 A[2][12];
    #pragma unroll
    for (int mm = 0; mm < 2; ++mm) {
        const __hip_bfloat16* ap = m1 + (long)(mbaseL + mm * 16 + l16) * 384 + quad * 8;
        #pragma unroll
        for (int kc = 0; kc < 12; ++kc)
            A[mm][kc] = *(const bf16x8*)(ap + kc * 32);
    }

    for (int ph = 0; ph < 2; ++ph) {
        if (ph) __syncthreads();
        for (int idx = tid; idx < 48 * 384; idx += 256) {
            int rr = idx / 384, cc = idx - rr * 384;
            wsm[rr * 392 + cc] = (short)bfbits(fw[(ph * 48 + rr) * 384 + cc]);
        }
        __syncthreads();
        for (int nt = 0; nt < 3; ++nt) {
            int n0 = nt * 16;
            const short* bp = &wsm[(n0 + l16) * 392 + quad * 8];
            bf16x8 B[12];
            #pragma unroll
            for (int kc = 0; kc < 12; ++kc)
                B[kc] = *(const bf16x8*)(bp + kc * 32);
            int c = ph * 48 + n0 + l16;             // output channel 0..95
            float bias = fb[c];
            #pragma unroll
            for (int mm = 0; mm < 2; ++mm) {
                f32x4 acc = {0.f, 0.f, 0.f, 0.f};
                #pragma unroll
                for (int kc = 0; kc < 12; ++kc)
                    acc = MFMA(A[mm][kc], B[kc], acc);
                int tok0 = t0 + mbaseL + mm * 16 + quad * 4;
                #pragma unroll
                for (int rg = 0; rg < 4; ++rg) {
                    long g = (long)(tok0 + rg) * 96 + c;
                    out[g] = t2[g] + acc[rg] + bias;
                }
            }
        }
    }
}

extern "C" void kernel_launch(void* const* d_in, const int* in_sizes, int n_in,
                              void* d_out, int out_size, void* d_ws, size_t ws_size,
                              hipStream_t stream)
{
    const float* x     = (const float*)d_in[0];
    const float* qkvw  = (const float*)d_in[1];
    const float* qkvb  = (const float*)d_in[2];
    const float* projw = (const float*)d_in[3];
    const float* projb = (const float*)d_in[4];
    const float* btab  = (const float*)d_in[5];
    const float* ln1g  = (const float*)d_in[6];
    const float* ln1b  = (const float*)d_in[7];
    const float* ln2g  = (const float*)d_in[8];
    const float* ln2b  = (const float*)d_in[9];
    const float* fc1w  = (const float*)d_in[10];
    const float* fc1b  = (const float*)d_in[11];
    const float* fc2w  = (const float*)d_in[12];
    const float* fc2b  = (const float*)d_in[13];
    float* out = (float*)d_out;

    if (ws_size < WS_NEED) {                // diagnostic: absmax ~1000 => ws too small
        k_fill<<<49152, 256, 0, stream>>>(out, out_size);
        return;
    }

    // ws layout (96 MiB peak):
    //  A [0, 24 MiB)   : h(bf16) -> o(bf16) -> m1 chunk(bf16, 32768 tok x 384)
    //  B [24, 96 MiB)  : qkv(bf16 72 MiB) -> { t2(fp32 48 MiB) ; h2(bf16 24 MiB) }
    char* ws = (char*)d_ws;
    __hip_bfloat16* hbuf  = (__hip_bfloat16*)(ws);
    __hip_bfloat16* qkvB  = (__hip_bfloat16*)(ws + 25165824);
    __hip_bfloat16* obuf  = hbuf;
    float*          t2buf = (float*)(ws + 25165824);
    __hip_bfloat16* h2buf = (__hip_bfloat16*)(ws + 75497472);
    __hip_bfloat16* m1buf = hbuf;

    k_ln1  <<<512,  256, 0, stream>>>(x, ln1g, ln1b, (u32*)hbuf);
    k_qkv_m<<<512,  256, 0, stream>>>(hbuf, qkvw, qkvb, qkvB);
    k_attn <<<1536, 128, 0, stream>>>(qkvB, btab, (u32*)obuf);
    k_proj_m<<<512, 256, 0, stream>>>(obuf, projw, projb, x, t2buf);
    k_ln2  <<<512,  256, 0, stream>>>(t2buf, ln2g, ln2b, (u32*)h2buf);
    for (int ch = 0; ch < 4; ++ch) {
        int t0 = ch * 32768;
        k_fc1_m<<<256, 256, 0, stream>>>(h2buf, fc1w, fc1b, m1buf, t0);
        k_fc2_m<<<256, 256, 0, stream>>>(m1buf, fc2w, fc2b, t2buf, out, t0);
    }
}

// Round 4
// 556.442 us; speedup vs baseline: 15.2795x; 1.7404x over previous
//
#include <hip/hip_runtime.h>
#include <hip/hip_bf16.h>

typedef unsigned int u32;
using bf16x8 = __attribute__((ext_vector_type(8))) short;
using f32x4  = __attribute__((ext_vector_type(4))) float;

#define QKV_STRIDE 12582912u   // elements per q/k/v tensor (512*3*256*32)
#define WS_NEED    100663296ull

__device__ __forceinline__ float bl(u32 u) { return __uint_as_float(u << 16); }
__device__ __forceinline__ float bh(u32 u) { return __uint_as_float(u & 0xffff0000u); }
__device__ __forceinline__ unsigned short bfbits(float f) {
    __hip_bfloat16 b = __float2bfloat16(f);
    return *(unsigned short*)&b;
}
__device__ __forceinline__ u32 pack2(float f0, float f1) {
    return ((u32)bfbits(f1) << 16) | (u32)bfbits(f0);
}

#define MFMA(a, b, c) __builtin_amdgcn_mfma_f32_16x16x32_bf16(a, b, c, 0, 0, 0)

// ---------------- guard: ws too small -> sentinel 1000 ----------------
__global__ __launch_bounds__(256) void k_fill(float* __restrict__ out, int n)
{
    int i = blockIdx.x * 256 + threadIdx.x;
    if (i < n) out[i] = 1000.0f;
}

// ---------------- K1: window-gather + LayerNorm1 -> h (bf16) [unchanged] ----------------
__global__ __launch_bounds__(256) void k_ln1(const float* __restrict__ x,
                                             const float* __restrict__ g1,
                                             const float* __restrict__ b1,
                                             u32* __restrict__ h)
{
    int t = blockIdx.x * 256 + threadIdx.x;
    int w = t >> 8, n = t & 255;
    int bb = w >> 8, hb = (w >> 4) & 15, wb = w & 15;
    int d = n >> 6, i = (n >> 3) & 7, j = n & 7;
    long off0 = (long)bb * 96 * 65536 + d * 16384 + (hb * 8 + i) * 128 + (wb * 8 + j);
    float s = 0.f, ss = 0.f;
    for (int c = 0; c < 96; ++c) {
        float v = x[off0 + (long)c * 65536];
        s += v; ss += v * v;
    }
    float mean = s * (1.f / 96.f);
    float var  = ss * (1.f / 96.f) - mean * mean;
    float rstd = rsqrtf(var + 1e-5f);
    u32* hr = h + (long)t * 48;
    for (int c2 = 0; c2 < 48; ++c2) {
        float v0 = x[off0 + (long)(2 * c2) * 65536];
        float v1 = x[off0 + (long)(2 * c2 + 1) * 65536];
        float y0 = (v0 - mean) * rstd * g1[2 * c2]     + b1[2 * c2];
        float y1 = (v1 - mean) * rstd * g1[2 * c2 + 1] + b1[2 * c2 + 1];
        hr[c2] = pack2(y0, y1);
    }
}

// ---------------- K2: QKV GEMM via MFMA [unchanged] ----------------
__global__ __launch_bounds__(256) void k_qkv_m(const __hip_bfloat16* __restrict__ h,
                                               const float* __restrict__ qkvw,
                                               const float* __restrict__ qkvb,
                                               __hip_bfloat16* __restrict__ qkv)
{
    __shared__ short wsm[288 * 96];
    int tid = threadIdx.x;
    for (int idx = tid; idx < 288 * 96; idx += 256) wsm[idx] = (short)bfbits(qkvw[idx]);
    __syncthreads();

    int wave = tid >> 6, lane = tid & 63;
    int quad = lane >> 4, l16 = lane & 15;
    int mbase = blockIdx.x * 256 + wave * 64;

    bf16x8 A[4][3];
    #pragma unroll
    for (int mm = 0; mm < 4; ++mm) {
        const __hip_bfloat16* ap = h + (long)(mbase + mm * 16 + l16) * 96 + quad * 8;
        A[mm][0] = *(const bf16x8*)(ap);
        A[mm][1] = *(const bf16x8*)(ap + 32);
        A[mm][2] = *(const bf16x8*)(ap + 64);
    }

    for (int nt = 0; nt < 18; ++nt) {
        int n0 = nt * 16;
        const short* bp = &wsm[(n0 + l16) * 96 + quad * 8];
        bf16x8 B0 = *(const bf16x8*)(bp);
        bf16x8 B1 = *(const bf16x8*)(bp + 32);
        bf16x8 B2 = *(const bf16x8*)(bp + 64);
        int r    = n0 + l16;
        int type = n0 / 96;
        int head = (n0 % 96) / 32;
        int dd   = r & 31;
        float bias = qkvb[r];
        float scl  = (type == 0) ? 0.17677669529663687f : 1.0f;
        long tbase = (long)type * QKV_STRIDE;
        #pragma unroll
        for (int mm = 0; mm < 4; ++mm) {
            f32x4 acc = {0.f, 0.f, 0.f, 0.f};
            acc = MFMA(A[mm][0], B0, acc);
            acc = MFMA(A[mm][1], B1, acc);
            acc = MFMA(A[mm][2], B2, acc);
            int tok0 = mbase + mm * 16 + quad * 4;
            int w = tok0 >> 8, nn = tok0 & 255;
            long dst0 = tbase + (long)(w * 3 + head) * 8192 + nn * 32 + dd;
            #pragma unroll
            for (int rg = 0; rg < 4; ++rg)
                qkv[dst0 + (long)rg * 32] = __float2bfloat16((acc[rg] + bias) * scl);
        }
    }
}

// ---------------- K3: window attention via MFMA (S^T = K*Q^T trick) ----------------
// block = (w,head); 4 waves x 64 queries. K,Q frags direct from global; V^T + P in LDS.
__global__ __launch_bounds__(256) void k_attn_m(const __hip_bfloat16* __restrict__ qkv,
                                                const float* __restrict__ btab,
                                                __hip_bfloat16* __restrict__ o)
{
    __shared__ short vt[32 * 264];        // V^T [d][key], pad 264 (b128-aligned rows)
    __shared__ short pm[4 * 16 * 264];    // per-wave P [query16][key256 pad]
    __shared__ float bs[961];             // bias table, this head
    int wh = blockIdx.x, head = wh % 3, w = wh / 3;
    int tid = threadIdx.x;

    const u32* vg = (const u32*)(qkv + 2u * QKV_STRIDE + (long)wh * 8192);
    for (int idx = tid; idx < 4096; idx += 256) {      // transpose V while staging
        u32 pv = vg[idx];
        int kr = idx >> 4, d0 = (idx & 15) * 2;
        vt[d0 * 264 + kr]       = (short)(pv & 0xffffu);
        vt[(d0 + 1) * 264 + kr] = (short)(pv >> 16);
    }
    for (int idx = tid; idx < 961; idx += 256) bs[idx] = btab[idx * 3 + head];
    __syncthreads();

    int wave = tid >> 6, lane = tid & 63, quad = lane >> 4, l16 = lane & 15;
    const __hip_bfloat16* qb = qkv + (long)wh * 8192;               // q pre-scaled
    const __hip_bfloat16* kb = qkv + QKV_STRIDE + (long)wh * 8192;
    short* pmw = &pm[wave * 16 * 264];

    bf16x8 kf[16];                        // all 256 keys, A-operand frags
    #pragma unroll
    for (int kt = 0; kt < 16; ++kt)
        kf[kt] = *(const bf16x8*)(kb + (kt * 16 + l16) * 32 + quad * 8);

    for (int g = 0; g < 4; ++g) {
        int qg = wave * 4 + g;            // query group (16 queries)
        bf16x8 qf = *(const bf16x8*)(qb + (qg * 16 + l16) * 32 + quad * 8);
        f32x4 s[16];
        #pragma unroll
        for (int kt = 0; kt < 16; ++kt) { // S^T tile: rows=keys, cols=queries
            f32x4 z = {0.f, 0.f, 0.f, 0.f};
            s[kt] = MFMA(kf[kt], qf, z);
        }
        // relative-position bias: lane holds (key kt*16+quad*4+rg, query qg*16+l16)
        #pragma unroll
        for (int kt = 0; kt < 16; ++kt) {
            int base = (qg - kt + 15) * 31 + (l16 - quad * 4 + 15);
            #pragma unroll
            for (int rg = 0; rg < 4; ++rg)
                s[kt][rg] += bs[base - rg];
        }
        // softmax over keys (in-lane 64 + quad shuffles)
        float mx = -1e30f;
        #pragma unroll
        for (int kt = 0; kt < 16; ++kt)
            #pragma unroll
            for (int rg = 0; rg < 4; ++rg) mx = fmaxf(mx, s[kt][rg]);
        mx = fmaxf(mx, __shfl_xor(mx, 16));
        mx = fmaxf(mx, __shfl_xor(mx, 32));
        float lsum = 0.f;
        #pragma unroll
        for (int kt = 0; kt < 16; ++kt)
            #pragma unroll
            for (int rg = 0; rg < 4; ++rg) {
                float p = __expf(s[kt][rg] - mx);
                s[kt][rg] = p; lsum += p;
            }
        lsum += __shfl_xor(lsum, 16);
        lsum += __shfl_xor(lsum, 32);
        float inv = 1.f / lsum;
        // P (pre-normalized) -> LDS in [query][key] layout
        #pragma unroll
        for (int kt = 0; kt < 16; ++kt)
            #pragma unroll
            for (int rg = 0; rg < 4; ++rg)
                pmw[l16 * 264 + kt * 16 + quad * 4 + rg] = (short)bfbits(s[kt][rg] * inv);
        // O = P*V : A = P rows (query), B = V^T rows (d)
        f32x4 a0 = {0.f, 0.f, 0.f, 0.f}, a1 = {0.f, 0.f, 0.f, 0.f};
        #pragma unroll
        for (int k2 = 0; k2 < 8; ++k2) {
            bf16x8 pf = *(const bf16x8*)&pmw[l16 * 264 + k2 * 32 + quad * 8];
            bf16x8 v0 = *(const bf16x8*)&vt[l16 * 264 + k2 * 32 + quad * 8];
            bf16x8 v1 = *(const bf16x8*)&vt[(16 + l16) * 264 + k2 * 32 + quad * 8];
            a0 = MFMA(pf, v0, a0);
            a1 = MFMA(pf, v1, a1);
        }
        #pragma unroll
        for (int rg = 0; rg < 4; ++rg) {
            int qrow = qg * 16 + quad * 4 + rg;
            __hip_bfloat16* op = o + (long)(w * 256 + qrow) * 96 + head * 32;
            op[l16]      = __float2bfloat16(a0[rg]);
            op[16 + l16] = __float2bfloat16(a1[rg]);
        }
    }
}

// ---------------- K4a: proj + residual(gathered x) -> t2 (fp32), MFMA [unchanged] ----------------
__global__ __launch_bounds__(256) void k_proj_m(const __hip_bfloat16* __restrict__ o,
                                                const float* __restrict__ pw,
                                                const float* __restrict__ pb,
                                                const float* __restrict__ x,
                                                float* __restrict__ t2)
{
    __shared__ short wsm[96 * 96];
    int tid = threadIdx.x;
    for (int idx = tid; idx < 96 * 96; idx += 256) wsm[idx] = (short)bfbits(pw[idx]);
    __syncthreads();

    int wave = tid >> 6, lane = tid & 63;
    int quad = lane >> 4, l16 = lane & 15;
    int mbase = blockIdx.x * 256 + wave * 64;

    bf16x8 A[4][3];
    #pragma unroll
    for (int mm = 0; mm < 4; ++mm) {
        const __hip_bfloat16* ap = o + (long)(mbase + mm * 16 + l16) * 96 + quad * 8;
        A[mm][0] = *(const bf16x8*)(ap);
        A[mm][1] = *(const bf16x8*)(ap + 32);
        A[mm][2] = *(const bf16x8*)(ap + 64);
    }

    for (int nt = 0; nt < 6; ++nt) {
        int n0 = nt * 16;
        const short* bp = &wsm[(n0 + l16) * 96 + quad * 8];
        bf16x8 B0 = *(const bf16x8*)(bp);
        bf16x8 B1 = *(const bf16x8*)(bp + 32);
        bf16x8 B2 = *(const bf16x8*)(bp + 64);
        int c = n0 + l16;
        float bias = pb[c];
        #pragma unroll
        for (int mm = 0; mm < 4; ++mm) {
            f32x4 acc = {0.f, 0.f, 0.f, 0.f};
            acc = MFMA(A[mm][0], B0, acc);
            acc = MFMA(A[mm][1], B1, acc);
            acc = MFMA(A[mm][2], B2, acc);
            int tok0 = mbase + mm * 16 + quad * 4;
            int w = tok0 >> 8, nn = tok0 & 255;
            int bb = w >> 8, hb = (w >> 4) & 15, wb = w & 15;
            int d = nn >> 6, ii = (nn >> 3) & 7, jj = nn & 7;
            long xoff = ((long)bb * 96 + c) * 65536 + d * 16384 + (hb * 8 + ii) * 128 + wb * 8 + jj;
            f32x4 xv = *(const f32x4*)&x[xoff];
            #pragma unroll
            for (int rg = 0; rg < 4; ++rg)
                t2[(long)(tok0 + rg) * 96 + c] = acc[rg] + bias + xv[rg];
        }
    }
}

// ---------------- K4b: LayerNorm2 -> h2 (bf16) [unchanged] ----------------
__global__ __launch_bounds__(256) void k_ln2(const float* __restrict__ t2,
                                             const float* __restrict__ g2,
                                             const float* __restrict__ b2,
                                             u32* __restrict__ h2)
{
    int t = blockIdx.x * 256 + threadIdx.x;
    const float* r = t2 + (long)t * 96;
    float s = 0.f, ss = 0.f;
    for (int c = 0; c < 96; ++c) {
        float v = r[c];
        s += v; ss += v * v;
    }
    float mean = s * (1.f / 96.f);
    float var  = ss * (1.f / 96.f) - mean * mean;
    float rstd = rsqrtf(var + 1e-5f);
    u32* outr = h2 + (long)t * 48;
    for (int c2 = 0; c2 < 48; ++c2) {
        float y0 = (r[2*c2]     - mean) * rstd * g2[2*c2]     + b2[2*c2];
        float y1 = (r[2*c2 + 1] - mean) * rstd * g2[2*c2 + 1] + b2[2*c2 + 1];
        outr[c2] = pack2(y0, y1);
    }
}

// ---------------- K5: fc1 + exact GELU via MFMA [unchanged] ----------------
__global__ __launch_bounds__(256) void k_fc1_m(const __hip_bfloat16* __restrict__ h2,
                                               const float* __restrict__ fw,
                                               const float* __restrict__ fb,
                                               __hip_bfloat16* __restrict__ m1, int t0)
{
    __shared__ short wsm[192 * 96];
    int tid = threadIdx.x;
    int wave = tid >> 6, lane = tid & 63;
    int quad = lane >> 4, l16 = lane & 15;
    int mbaseL = blockIdx.x * 128 + wave * 32;

    bf16x8 A[2][3];
    #pragma unroll
    for (int mm = 0; mm < 2; ++mm) {
        const __hip_bfloat16* ap = h2 + (long)(t0 + mbaseL + mm * 16 + l16) * 96 + quad * 8;
        A[mm][0] = *(const bf16x8*)(ap);
        A[mm][1] = *(const bf16x8*)(ap + 32);
        A[mm][2] = *(const bf16x8*)(ap + 64);
    }

    const float is2 = 0.70710678118654752440f;
    for (int ph = 0; ph < 2; ++ph) {
        if (ph) __syncthreads();
        for (int idx = tid; idx < 192 * 96; idx += 256)
            wsm[idx] = (short)bfbits(fw[ph * 192 * 96 + idx]);
        __syncthreads();
        for (int nt = 0; nt < 12; ++nt) {
            int n0 = nt * 16;
            const short* bp = &wsm[(n0 + l16) * 96 + quad * 8];
            bf16x8 B0 = *(const bf16x8*)(bp);
            bf16x8 B1 = *(const bf16x8*)(bp + 32);
            bf16x8 B2 = *(const bf16x8*)(bp + 64);
            int r = ph * 192 + n0 + l16;
            float bias = fb[r];
            #pragma unroll
            for (int mm = 0; mm < 2; ++mm) {
                f32x4 acc = {0.f, 0.f, 0.f, 0.f};
                acc = MFMA(A[mm][0], B0, acc);
                acc = MFMA(A[mm][1], B1, acc);
                acc = MFMA(A[mm][2], B2, acc);
                int tokL0 = mbaseL + mm * 16 + quad * 4;
                #pragma unroll
                for (int rg = 0; rg < 4; ++rg) {
                    float v = acc[rg] + bias;
                    v = 0.5f * v * (1.f + erff(v * is2));
                    m1[(long)(tokL0 + rg) * 384 + r] = __float2bfloat16(v);
                }
            }
        }
    }
}

// ---------------- K6: fc2 + residual -> out via MFMA [unchanged] ----------------
__global__ __launch_bounds__(256) void k_fc2_m(const __hip_bfloat16* __restrict__ m1,
                                               const float* __restrict__ fw,
                                               const float* __restrict__ fb,
                                               const float* __restrict__ t2,
                                               float* __restrict__ out, int t0)
{
    __shared__ short wsm[48 * 392];
    int tid = threadIdx.x;
    int wave = tid >> 6, lane = tid & 63;
    int quad = lane >> 4, l16 = lane & 15;
    int mbaseL = blockIdx.x * 128 + wave * 32;

    bf16x8 A[2][12];
    #pragma unroll
    for (int mm = 0; mm < 2; ++mm) {
        const __hip_bfloat16* ap = m1 + (long)(mbaseL + mm * 16 + l16) * 384 + quad * 8;
        #pragma unroll
        for (int kc = 0; kc < 12; ++kc)
            A[mm][kc] = *(const bf16x8*)(ap + kc * 32);
    }

    for (int ph = 0; ph < 2; ++ph) {
        if (ph) __syncthreads();
        for (int idx = tid; idx < 48 * 384; idx += 256) {
            int rr = idx / 384, cc = idx - rr * 384;
            wsm[rr * 392 + cc] = (short)bfbits(fw[(ph * 48 + rr) * 384 + cc]);
        }
        __syncthreads();
        for (int nt = 0; nt < 3; ++nt) {
            int n0 = nt * 16;
            const short* bp = &wsm[(n0 + l16) * 392 + quad * 8];
            bf16x8 B[12];
            #pragma unroll
            for (int kc = 0; kc < 12; ++kc)
                B[kc] = *(const bf16x8*)(bp + kc * 32);
            int c = ph * 48 + n0 + l16;
            float bias = fb[c];
            #pragma unroll
            for (int mm = 0; mm < 2; ++mm) {
                f32x4 acc = {0.f, 0.f, 0.f, 0.f};
                #pragma unroll
                for (int kc = 0; kc < 12; ++kc)
                    acc = MFMA(A[mm][kc], B[kc], acc);
                int tok0 = t0 + mbaseL + mm * 16 + quad * 4;
                #pragma unroll
                for (int rg = 0; rg < 4; ++rg) {
                    long g = (long)(tok0 + rg) * 96 + c;
                    out[g] = t2[g] + acc[rg] + bias;
                }
            }
        }
    }
}

extern "C" void kernel_launch(void* const* d_in, const int* in_sizes, int n_in,
                              void* d_out, int out_size, void* d_ws, size_t ws_size,
                              hipStream_t stream)
{
    const float* x     = (const float*)d_in[0];
    const float* qkvw  = (const float*)d_in[1];
    const float* qkvb  = (const float*)d_in[2];
    const float* projw = (const float*)d_in[3];
    const float* projb = (const float*)d_in[4];
    const float* btab  = (const float*)d_in[5];
    const float* ln1g  = (const float*)d_in[6];
    const float* ln1b  = (const float*)d_in[7];
    const float* ln2g  = (const float*)d_in[8];
    const float* ln2b  = (const float*)d_in[9];
    const float* fc1w  = (const float*)d_in[10];
    const float* fc1b  = (const float*)d_in[11];
    const float* fc2w  = (const float*)d_in[12];
    const float* fc2b  = (const float*)d_in[13];
    float* out = (float*)d_out;

    if (ws_size < WS_NEED) {
        k_fill<<<49152, 256, 0, stream>>>(out, out_size);
        return;
    }

    // ws layout (96 MiB peak):
    //  A [0, 24 MiB)   : h(bf16) -> o(bf16) -> m1 chunk(bf16, 32768 tok x 384)
    //  B [24, 96 MiB)  : qkv(bf16 72 MiB) -> { t2(fp32 48 MiB) ; h2(bf16 24 MiB) }
    char* ws = (char*)d_ws;
    __hip_bfloat16* hbuf  = (__hip_bfloat16*)(ws);
    __hip_bfloat16* qkvB  = (__hip_bfloat16*)(ws + 25165824);
    __hip_bfloat16* obuf  = hbuf;
    float*          t2buf = (float*)(ws + 25165824);
    __hip_bfloat16* h2buf = (__hip_bfloat16*)(ws + 75497472);
    __hip_bfloat16* m1buf = hbuf;

    k_ln1   <<<512,  256, 0, stream>>>(x, ln1g, ln1b, (u32*)hbuf);
    k_qkv_m <<<512,  256, 0, stream>>>(hbuf, qkvw, qkvb, qkvB);
    k_attn_m<<<1536, 256, 0, stream>>>(qkvB, btab, obuf);
    k_proj_m<<<512,  256, 0, stream>>>(obuf, projw, projb, x, t2buf);
    k_ln2   <<<512,  256, 0, stream>>>(t2buf, ln2g, ln2b, (u32*)h2buf);
    for (int ch = 0; ch < 4; ++ch) {
        int t0 = ch * 32768;
        k_fc1_m<<<256, 256, 0, stream>>>(h2buf, fc1w, fc1b, m1buf, t0);
        k_fc2_m<<<256, 256, 0, stream>>>(m1buf, fc2w, fc2b, t2buf, out, t0);
    }
}

// Round 5
// 460.631 us; speedup vs baseline: 18.4577x; 1.2080x over previous
//
#include <hip/hip_runtime.h>
#include <hip/hip_bf16.h>

typedef unsigned int u32;
using bf16x8 = __attribute__((ext_vector_type(8))) short;
using f32x4  = __attribute__((ext_vector_type(4))) float;

#define QKV_STRIDE 12582912u   // elements per q/k/v tensor (512*3*256*32)
#define WS_NEED    100663296ull

__device__ __forceinline__ float bl(u32 u) { return __uint_as_float(u << 16); }
__device__ __forceinline__ float bh(u32 u) { return __uint_as_float(u & 0xffff0000u); }
__device__ __forceinline__ unsigned short bfbits(float f) {
    __hip_bfloat16 b = __float2bfloat16(f);
    return *(unsigned short*)&b;
}
__device__ __forceinline__ u32 pack2(float f0, float f1) {
    return ((u32)bfbits(f1) << 16) | (u32)bfbits(f0);
}

#define MFMA(a, b, c) __builtin_amdgcn_mfma_f32_16x16x32_bf16(a, b, c, 0, 0, 0)

// ---------------- guard: ws too small -> sentinel 1000 ----------------
__global__ __launch_bounds__(256) void k_fill(float* __restrict__ out, int n)
{
    int i = blockIdx.x * 256 + threadIdx.x;
    if (i < n) out[i] = 1000.0f;
}

// ---------------- K1: coalesced gather + LayerNorm1 -> h (bf16) ----------------
// block = (bb,d,hh): stage x[bb, :, d, hh, :] (96x128 fp32) in LDS via float4.
__global__ __launch_bounds__(256) void k_ln1_c(const float* __restrict__ x,
                                               const float* __restrict__ g1,
                                               const float* __restrict__ b1,
                                               u32* __restrict__ h)
{
    __shared__ float xs[96 * 128];
    __shared__ float ps[256], pss[256], mr[128], rs[128];
    int blk = blockIdx.x;
    int hh = blk & 127, d = (blk >> 7) & 3, bb = blk >> 9;
    long base = (long)bb * 6291456 + (long)d * 16384 + hh * 128;
    for (int i = threadIdx.x; i < 3072; i += 256) {
        int c = i >> 5, w4 = i & 31;
        ((float4*)xs)[i] = *(const float4*)(x + base + (long)c * 65536 + w4 * 4);
    }
    __syncthreads();

    int tid = threadIdx.x, half = tid >> 7, ww = tid & 127;
    int c0 = half * 48;
    float s = 0.f, ssq = 0.f;
    #pragma unroll 8
    for (int c = c0; c < c0 + 48; ++c) {
        float v = xs[c * 128 + ww];
        s += v; ssq += v * v;
    }
    ps[tid] = s; pss[tid] = ssq;
    __syncthreads();
    if (half == 0) {
        float st = ps[ww] + ps[128 + ww], sst = pss[ww] + pss[128 + ww];
        float mean = st * (1.f / 96.f);
        float var  = sst * (1.f / 96.f) - mean * mean;
        mr[ww] = mean; rs[ww] = rsqrtf(var + 1e-5f);
    }
    __syncthreads();
    float mean = mr[ww], rstd = rs[ww];

    int w = (bb << 8) + (hh >> 3) * 16 + (ww >> 3);
    int t = (w << 8) + d * 64 + (hh & 7) * 8 + (ww & 7);
    uint4* hq = (uint4*)(h + (long)t * 48 + half * 24);
    #pragma unroll
    for (int k = 0; k < 6; ++k) {
        int c = c0 + 8 * k;
        u32 q0 = pack2((xs[(c+0)*128+ww]-mean)*rstd*g1[c+0]+b1[c+0],
                       (xs[(c+1)*128+ww]-mean)*rstd*g1[c+1]+b1[c+1]);
        u32 q1 = pack2((xs[(c+2)*128+ww]-mean)*rstd*g1[c+2]+b1[c+2],
                       (xs[(c+3)*128+ww]-mean)*rstd*g1[c+3]+b1[c+3]);
        u32 q2 = pack2((xs[(c+4)*128+ww]-mean)*rstd*g1[c+4]+b1[c+4],
                       (xs[(c+5)*128+ww]-mean)*rstd*g1[c+5]+b1[c+5]);
        u32 q3 = pack2((xs[(c+6)*128+ww]-mean)*rstd*g1[c+6]+b1[c+6],
                       (xs[(c+7)*128+ww]-mean)*rstd*g1[c+7]+b1[c+7]);
        hq[k] = make_uint4(q0, q1, q2, q3);
    }
}

// ---------------- K2: QKV GEMM via MFMA [unchanged] ----------------
__global__ __launch_bounds__(256) void k_qkv_m(const __hip_bfloat16* __restrict__ h,
                                               const float* __restrict__ qkvw,
                                               const float* __restrict__ qkvb,
                                               __hip_bfloat16* __restrict__ qkv)
{
    __shared__ short wsm[288 * 96];
    int tid = threadIdx.x;
    for (int idx = tid; idx < 288 * 96; idx += 256) wsm[idx] = (short)bfbits(qkvw[idx]);
    __syncthreads();

    int wave = tid >> 6, lane = tid & 63;
    int quad = lane >> 4, l16 = lane & 15;
    int mbase = blockIdx.x * 256 + wave * 64;

    bf16x8 A[4][3];
    #pragma unroll
    for (int mm = 0; mm < 4; ++mm) {
        const __hip_bfloat16* ap = h + (long)(mbase + mm * 16 + l16) * 96 + quad * 8;
        A[mm][0] = *(const bf16x8*)(ap);
        A[mm][1] = *(const bf16x8*)(ap + 32);
        A[mm][2] = *(const bf16x8*)(ap + 64);
    }

    for (int nt = 0; nt < 18; ++nt) {
        int n0 = nt * 16;
        const short* bp = &wsm[(n0 + l16) * 96 + quad * 8];
        bf16x8 B0 = *(const bf16x8*)(bp);
        bf16x8 B1 = *(const bf16x8*)(bp + 32);
        bf16x8 B2 = *(const bf16x8*)(bp + 64);
        int r    = n0 + l16;
        int type = n0 / 96;
        int head = (n0 % 96) / 32;
        int dd   = r & 31;
        float bias = qkvb[r];
        float scl  = (type == 0) ? 0.17677669529663687f : 1.0f;
        long tbase = (long)type * QKV_STRIDE;
        #pragma unroll
        for (int mm = 0; mm < 4; ++mm) {
            f32x4 acc = {0.f, 0.f, 0.f, 0.f};
            acc = MFMA(A[mm][0], B0, acc);
            acc = MFMA(A[mm][1], B1, acc);
            acc = MFMA(A[mm][2], B2, acc);
            int tok0 = mbase + mm * 16 + quad * 4;
            int w = tok0 >> 8, nn = tok0 & 255;
            long dst0 = tbase + (long)(w * 3 + head) * 8192 + nn * 32 + dd;
            #pragma unroll
            for (int rg = 0; rg < 4; ++rg)
                qkv[dst0 + (long)rg * 32] = __float2bfloat16((acc[rg] + bias) * scl);
        }
    }
}

// ---------------- K3: window attention via MFMA [unchanged] ----------------
__global__ __launch_bounds__(256) void k_attn_m(const __hip_bfloat16* __restrict__ qkv,
                                                const float* __restrict__ btab,
                                                __hip_bfloat16* __restrict__ o)
{
    __shared__ short vt[32 * 264];
    __shared__ short pm[4 * 16 * 264];
    __shared__ float bs[961];
    int wh = blockIdx.x, head = wh % 3, w = wh / 3;
    int tid = threadIdx.x;

    const u32* vg = (const u32*)(qkv + 2u * QKV_STRIDE + (long)wh * 8192);
    for (int idx = tid; idx < 4096; idx += 256) {
        u32 pv = vg[idx];
        int kr = idx >> 4, d0 = (idx & 15) * 2;
        vt[d0 * 264 + kr]       = (short)(pv & 0xffffu);
        vt[(d0 + 1) * 264 + kr] = (short)(pv >> 16);
    }
    for (int idx = tid; idx < 961; idx += 256) bs[idx] = btab[idx * 3 + head];
    __syncthreads();

    int wave = tid >> 6, lane = tid & 63, quad = lane >> 4, l16 = lane & 15;
    const __hip_bfloat16* qb = qkv + (long)wh * 8192;
    const __hip_bfloat16* kb = qkv + QKV_STRIDE + (long)wh * 8192;
    short* pmw = &pm[wave * 16 * 264];

    bf16x8 kf[16];
    #pragma unroll
    for (int kt = 0; kt < 16; ++kt)
        kf[kt] = *(const bf16x8*)(kb + (kt * 16 + l16) * 32 + quad * 8);

    for (int g = 0; g < 4; ++g) {
        int qg = wave * 4 + g;
        bf16x8 qf = *(const bf16x8*)(qb + (qg * 16 + l16) * 32 + quad * 8);
        f32x4 s[16];
        #pragma unroll
        for (int kt = 0; kt < 16; ++kt) {
            f32x4 z = {0.f, 0.f, 0.f, 0.f};
            s[kt] = MFMA(kf[kt], qf, z);
        }
        #pragma unroll
        for (int kt = 0; kt < 16; ++kt) {
            int base = (qg - kt + 15) * 31 + (l16 - quad * 4 + 15);
            #pragma unroll
            for (int rg = 0; rg < 4; ++rg)
                s[kt][rg] += bs[base - rg];
        }
        float mx = -1e30f;
        #pragma unroll
        for (int kt = 0; kt < 16; ++kt)
            #pragma unroll
            for (int rg = 0; rg < 4; ++rg) mx = fmaxf(mx, s[kt][rg]);
        mx = fmaxf(mx, __shfl_xor(mx, 16));
        mx = fmaxf(mx, __shfl_xor(mx, 32));
        float lsum = 0.f;
        #pragma unroll
        for (int kt = 0; kt < 16; ++kt)
            #pragma unroll
            for (int rg = 0; rg < 4; ++rg) {
                float p = __expf(s[kt][rg] - mx);
                s[kt][rg] = p; lsum += p;
            }
        lsum += __shfl_xor(lsum, 16);
        lsum += __shfl_xor(lsum, 32);
        float inv = 1.f / lsum;
        #pragma unroll
        for (int kt = 0; kt < 16; ++kt)
            #pragma unroll
            for (int rg = 0; rg < 4; ++rg)
                pmw[l16 * 264 + kt * 16 + quad * 4 + rg] = (short)bfbits(s[kt][rg] * inv);
        f32x4 a0 = {0.f, 0.f, 0.f, 0.f}, a1 = {0.f, 0.f, 0.f, 0.f};
        #pragma unroll
        for (int k2 = 0; k2 < 8; ++k2) {
            bf16x8 pf = *(const bf16x8*)&pmw[l16 * 264 + k2 * 32 + quad * 8];
            bf16x8 v0 = *(const bf16x8*)&vt[l16 * 264 + k2 * 32 + quad * 8];
            bf16x8 v1 = *(const bf16x8*)&vt[(16 + l16) * 264 + k2 * 32 + quad * 8];
            a0 = MFMA(pf, v0, a0);
            a1 = MFMA(pf, v1, a1);
        }
        #pragma unroll
        for (int rg = 0; rg < 4; ++rg) {
            int qrow = qg * 16 + quad * 4 + rg;
            __hip_bfloat16* op = o + (long)(w * 256 + qrow) * 96 + head * 32;
            op[l16]      = __float2bfloat16(a0[rg]);
            op[16 + l16] = __float2bfloat16(a1[rg]);
        }
    }
}

// ---------------- K4a: proj (no residual) -> pbuf (bf16), MFMA ----------------
__global__ __launch_bounds__(256) void k_proj_nr(const __hip_bfloat16* __restrict__ o,
                                                 const float* __restrict__ pw,
                                                 const float* __restrict__ pb,
                                                 __hip_bfloat16* __restrict__ pbuf)
{
    __shared__ short wsm[96 * 96];
    int tid = threadIdx.x;
    for (int idx = tid; idx < 96 * 96; idx += 256) wsm[idx] = (short)bfbits(pw[idx]);
    __syncthreads();

    int wave = tid >> 6, lane = tid & 63;
    int quad = lane >> 4, l16 = lane & 15;
    int mbase = blockIdx.x * 256 + wave * 64;

    bf16x8 A[4][3];
    #pragma unroll
    for (int mm = 0; mm < 4; ++mm) {
        const __hip_bfloat16* ap = o + (long)(mbase + mm * 16 + l16) * 96 + quad * 8;
        A[mm][0] = *(const bf16x8*)(ap);
        A[mm][1] = *(const bf16x8*)(ap + 32);
        A[mm][2] = *(const bf16x8*)(ap + 64);
    }

    for (int nt = 0; nt < 6; ++nt) {
        int n0 = nt * 16;
        const short* bp = &wsm[(n0 + l16) * 96 + quad * 8];
        bf16x8 B0 = *(const bf16x8*)(bp);
        bf16x8 B1 = *(const bf16x8*)(bp + 32);
        bf16x8 B2 = *(const bf16x8*)(bp + 64);
        int c = n0 + l16;
        float bias = pb[c];
        #pragma unroll
        for (int mm = 0; mm < 4; ++mm) {
            f32x4 acc = {0.f, 0.f, 0.f, 0.f};
            acc = MFMA(A[mm][0], B0, acc);
            acc = MFMA(A[mm][1], B1, acc);
            acc = MFMA(A[mm][2], B2, acc);
            int tok0 = mbase + mm * 16 + quad * 4;
            #pragma unroll
            for (int rg = 0; rg < 4; ++rg)
                pbuf[(long)(tok0 + rg) * 96 + c] = __float2bfloat16(acc[rg] + bias);
        }
    }
}

// ---------------- K4b: residual(coalesced x) + LayerNorm2 -> t2 (fp32), h2 (bf16) ----------------
__global__ __launch_bounds__(256) void k_addln2(const float* __restrict__ x,
                                                const __hip_bfloat16* __restrict__ pbuf,
                                                const float* __restrict__ g2,
                                                const float* __restrict__ b2,
                                                float* __restrict__ t2,
                                                u32* __restrict__ h2)
{
    __shared__ float xs[96 * 128];
    __shared__ float ps[256], pss[256], mr[128], rs[128];
    int blk = blockIdx.x;
    int hh = blk & 127, d = (blk >> 7) & 3, bb = blk >> 9;
    long base = (long)bb * 6291456 + (long)d * 16384 + hh * 128;
    for (int i = threadIdx.x; i < 3072; i += 256) {
        int c = i >> 5, w4 = i & 31;
        ((float4*)xs)[i] = *(const float4*)(x + base + (long)c * 65536 + w4 * 4);
    }
    __syncthreads();

    int tid = threadIdx.x, half = tid >> 7, ww = tid & 127;
    int c0 = half * 48;
    int w = (bb << 8) + (hh >> 3) * 16 + (ww >> 3);
    int t = (w << 8) + d * 64 + (hh & 7) * 8 + (ww & 7);

    const u32* pr = (const u32*)pbuf + (long)t * 48 + half * 24;
    float pv[48];
    float s = 0.f, ssq = 0.f;
    #pragma unroll
    for (int k = 0; k < 24; ++k) {
        u32 u = pr[k];
        float v0 = bl(u) + xs[(c0 + 2 * k) * 128 + ww];
        float v1 = bh(u) + xs[(c0 + 2 * k + 1) * 128 + ww];
        pv[2 * k] = v0; pv[2 * k + 1] = v1;
        s += v0 + v1; ssq += v0 * v0 + v1 * v1;
    }
    ps[tid] = s; pss[tid] = ssq;
    __syncthreads();
    if (half == 0) {
        float st = ps[ww] + ps[128 + ww], sst = pss[ww] + pss[128 + ww];
        float mean = st * (1.f / 96.f);
        float var  = sst * (1.f / 96.f) - mean * mean;
        mr[ww] = mean; rs[ww] = rsqrtf(var + 1e-5f);
    }
    __syncthreads();
    float mean = mr[ww], rstd = rs[ww];

    float4* t2q = (float4*)(t2 + (long)t * 96 + c0);
    #pragma unroll
    for (int k = 0; k < 12; ++k) {
        float4 v = {pv[4*k], pv[4*k+1], pv[4*k+2], pv[4*k+3]};
        t2q[k] = v;
    }
    uint4* hq = (uint4*)(h2 + (long)t * 48 + half * 24);
    #pragma unroll
    for (int k = 0; k < 6; ++k) {
        int c = c0 + 8 * k;
        u32 q0 = pack2((pv[8*k+0]-mean)*rstd*g2[c+0]+b2[c+0],
                       (pv[8*k+1]-mean)*rstd*g2[c+1]+b2[c+1]);
        u32 q1 = pack2((pv[8*k+2]-mean)*rstd*g2[c+2]+b2[c+2],
                       (pv[8*k+3]-mean)*rstd*g2[c+3]+b2[c+3]);
        u32 q2 = pack2((pv[8*k+4]-mean)*rstd*g2[c+4]+b2[c+4],
                       (pv[8*k+5]-mean)*rstd*g2[c+5]+b2[c+5]);
        u32 q3 = pack2((pv[8*k+6]-mean)*rstd*g2[c+6]+b2[c+6],
                       (pv[8*k+7]-mean)*rstd*g2[c+7]+b2[c+7]);
        hq[k] = make_uint4(q0, q1, q2, q3);
    }
}

// ---------------- K5: fc1 + exact GELU via MFMA [unchanged] ----------------
__global__ __launch_bounds__(256) void k_fc1_m(const __hip_bfloat16* __restrict__ h2,
                                               const float* __restrict__ fw,
                                               const float* __restrict__ fb,
                                               __hip_bfloat16* __restrict__ m1, int t0)
{
    __shared__ short wsm[192 * 96];
    int tid = threadIdx.x;
    int wave = tid >> 6, lane = tid & 63;
    int quad = lane >> 4, l16 = lane & 15;
    int mbaseL = blockIdx.x * 128 + wave * 32;

    bf16x8 A[2][3];
    #pragma unroll
    for (int mm = 0; mm < 2; ++mm) {
        const __hip_bfloat16* ap = h2 + (long)(t0 + mbaseL + mm * 16 + l16) * 96 + quad * 8;
        A[mm][0] = *(const bf16x8*)(ap);
        A[mm][1] = *(const bf16x8*)(ap + 32);
        A[mm][2] = *(const bf16x8*)(ap + 64);
    }

    const float is2 = 0.70710678118654752440f;
    for (int ph = 0; ph < 2; ++ph) {
        if (ph) __syncthreads();
        for (int idx = tid; idx < 192 * 96; idx += 256)
            wsm[idx] = (short)bfbits(fw[ph * 192 * 96 + idx]);
        __syncthreads();
        for (int nt = 0; nt < 12; ++nt) {
            int n0 = nt * 16;
            const short* bp = &wsm[(n0 + l16) * 96 + quad * 8];
            bf16x8 B0 = *(const bf16x8*)(bp);
            bf16x8 B1 = *(const bf16x8*)(bp + 32);
            bf16x8 B2 = *(const bf16x8*)(bp + 64);
            int r = ph * 192 + n0 + l16;
            float bias = fb[r];
            #pragma unroll
            for (int mm = 0; mm < 2; ++mm) {
                f32x4 acc = {0.f, 0.f, 0.f, 0.f};
                acc = MFMA(A[mm][0], B0, acc);
                acc = MFMA(A[mm][1], B1, acc);
                acc = MFMA(A[mm][2], B2, acc);
                int tokL0 = mbaseL + mm * 16 + quad * 4;
                #pragma unroll
                for (int rg = 0; rg < 4; ++rg) {
                    float v = acc[rg] + bias;
                    v = 0.5f * v * (1.f + erff(v * is2));
                    m1[(long)(tokL0 + rg) * 384 + r] = __float2bfloat16(v);
                }
            }
        }
    }
}

// ---------------- K6: fc2 + residual -> out via MFMA [unchanged] ----------------
__global__ __launch_bounds__(256) void k_fc2_m(const __hip_bfloat16* __restrict__ m1,
                                               const float* __restrict__ fw,
                                               const float* __restrict__ fb,
                                               const float* __restrict__ t2,
                                               float* __restrict__ out, int t0)
{
    __shared__ short wsm[48 * 392];
    int tid = threadIdx.x;
    int wave = tid >> 6, lane = tid & 63;
    int quad = lane >> 4, l16 = lane & 15;
    int mbaseL = blockIdx.x * 128 + wave * 32;

    bf16x8 A[2][12];
    #pragma unroll
    for (int mm = 0; mm < 2; ++mm) {
        const __hip_bfloat16* ap = m1 + (long)(mbaseL + mm * 16 + l16) * 384 + quad * 8;
        #pragma unroll
        for (int kc = 0; kc < 12; ++kc)
            A[mm][kc] = *(const bf16x8*)(ap + kc * 32);
    }

    for (int ph = 0; ph < 2; ++ph) {
        if (ph) __syncthreads();
        for (int idx = tid; idx < 48 * 384; idx += 256) {
            int rr = idx / 384, cc = idx - rr * 384;
            wsm[rr * 392 + cc] = (short)bfbits(fw[(ph * 48 + rr) * 384 + cc]);
        }
        __syncthreads();
        for (int nt = 0; nt < 3; ++nt) {
            int n0 = nt * 16;
            const short* bp = &wsm[(n0 + l16) * 392 + quad * 8];
            bf16x8 B[12];
            #pragma unroll
            for (int kc = 0; kc < 12; ++kc)
                B[kc] = *(const bf16x8*)(bp + kc * 32);
            int c = ph * 48 + n0 + l16;
            float bias = fb[c];
            #pragma unroll
            for (int mm = 0; mm < 2; ++mm) {
                f32x4 acc = {0.f, 0.f, 0.f, 0.f};
                #pragma unroll
                for (int kc = 0; kc < 12; ++kc)
                    acc = MFMA(A[mm][kc], B[kc], acc);
                int tok0 = t0 + mbaseL + mm * 16 + quad * 4;
                #pragma unroll
                for (int rg = 0; rg < 4; ++rg) {
                    long g = (long)(tok0 + rg) * 96 + c;
                    out[g] = t2[g] + acc[rg] + bias;
                }
            }
        }
    }
}

extern "C" void kernel_launch(void* const* d_in, const int* in_sizes, int n_in,
                              void* d_out, int out_size, void* d_ws, size_t ws_size,
                              hipStream_t stream)
{
    const float* x     = (const float*)d_in[0];
    const float* qkvw  = (const float*)d_in[1];
    const float* qkvb  = (const float*)d_in[2];
    const float* projw = (const float*)d_in[3];
    const float* projb = (const float*)d_in[4];
    const float* btab  = (const float*)d_in[5];
    const float* ln1g  = (const float*)d_in[6];
    const float* ln1b  = (const float*)d_in[7];
    const float* ln2g  = (const float*)d_in[8];
    const float* ln2b  = (const float*)d_in[9];
    const float* fc1w  = (const float*)d_in[10];
    const float* fc1b  = (const float*)d_in[11];
    const float* fc2w  = (const float*)d_in[12];
    const float* fc2b  = (const float*)d_in[13];
    float* out = (float*)d_out;

    if (ws_size < WS_NEED) {
        k_fill<<<49152, 256, 0, stream>>>(out, out_size);
        return;
    }

    // ws lifetimes (96 MiB):
    //  [0,72)  : qkv(bf16) -> t2(fp32 48 MiB in [0,48))
    //  [48,72) : pbuf(bf16) -> m1 chunk(bf16)
    //  [72,96) : h(bf16) -> o(bf16) -> h2(bf16)
    char* ws = (char*)d_ws;
    __hip_bfloat16* qkvB  = (__hip_bfloat16*)(ws);
    float*          t2buf = (float*)(ws);
    __hip_bfloat16* pbuf  = (__hip_bfloat16*)(ws + 50331648);
    __hip_bfloat16* m1buf = (__hip_bfloat16*)(ws + 50331648);
    __hip_bfloat16* hbuf  = (__hip_bfloat16*)(ws + 75497472);
    __hip_bfloat16* obuf  = hbuf;
    __hip_bfloat16* h2buf = hbuf;

    k_ln1_c <<<1024, 256, 0, stream>>>(x, ln1g, ln1b, (u32*)hbuf);
    k_qkv_m <<<512,  256, 0, stream>>>(hbuf, qkvw, qkvb, qkvB);
    k_attn_m<<<1536, 256, 0, stream>>>(qkvB, btab, obuf);
    k_proj_nr<<<512, 256, 0, stream>>>(obuf, projw, projb, pbuf);
    k_addln2<<<1024, 256, 0, stream>>>(x, pbuf, ln2g, ln2b, t2buf, (u32*)h2buf);
    for (int ch = 0; ch < 4; ++ch) {
        int t0 = ch * 32768;
        k_fc1_m<<<256, 256, 0, stream>>>(h2buf, fc1w, fc1b, m1buf, t0);
        k_fc2_m<<<256, 256, 0, stream>>>(m1buf, fc2w, fc2b, t2buf, out, t0);
    }
}

// Round 6
// 371.978 us; speedup vs baseline: 22.8567x; 1.2383x over previous
//
#include <hip/hip_runtime.h>
#include <hip/hip_bf16.h>

typedef unsigned int u32;
using bf16x8 = __attribute__((ext_vector_type(8))) short;
using f32x4  = __attribute__((ext_vector_type(4))) float;

#define QKV_STRIDE 12582912u   // elements per q/k/v tensor (512*3*256*32)
#define WS_NEED    100663296ull

__device__ __forceinline__ float bl(u32 u) { return __uint_as_float(u << 16); }
__device__ __forceinline__ float bh(u32 u) { return __uint_as_float(u & 0xffff0000u); }
__device__ __forceinline__ unsigned short bfbits(float f) {
    __hip_bfloat16 b = __float2bfloat16(f);
    return *(unsigned short*)&b;
}
__device__ __forceinline__ u32 pack2(float f0, float f1) {
    return ((u32)bfbits(f1) << 16) | (u32)bfbits(f0);
}

#define MFMA(a, b, c) __builtin_amdgcn_mfma_f32_16x16x32_bf16(a, b, c, 0, 0, 0)

// ---------------- guard: ws too small -> sentinel 1000 ----------------
__global__ __launch_bounds__(256) void k_fill(float* __restrict__ out, int n)
{
    int i = blockIdx.x * 256 + threadIdx.x;
    if (i < n) out[i] = 1000.0f;
}

// ---------------- K1: coalesced gather + LayerNorm1 -> h (bf16) [unchanged] ----------------
__global__ __launch_bounds__(256) void k_ln1_c(const float* __restrict__ x,
                                               const float* __restrict__ g1,
                                               const float* __restrict__ b1,
                                               u32* __restrict__ h)
{
    __shared__ float xs[96 * 128];
    __shared__ float ps[256], pss[256], mr[128], rs[128];
    int blk = blockIdx.x;
    int hh = blk & 127, d = (blk >> 7) & 3, bb = blk >> 9;
    long base = (long)bb * 6291456 + (long)d * 16384 + hh * 128;
    for (int i = threadIdx.x; i < 3072; i += 256) {
        int c = i >> 5, w4 = i & 31;
        ((float4*)xs)[i] = *(const float4*)(x + base + (long)c * 65536 + w4 * 4);
    }
    __syncthreads();

    int tid = threadIdx.x, half = tid >> 7, ww = tid & 127;
    int c0 = half * 48;
    float s = 0.f, ssq = 0.f;
    #pragma unroll 8
    for (int c = c0; c < c0 + 48; ++c) {
        float v = xs[c * 128 + ww];
        s += v; ssq += v * v;
    }
    ps[tid] = s; pss[tid] = ssq;
    __syncthreads();
    if (half == 0) {
        float st = ps[ww] + ps[128 + ww], sst = pss[ww] + pss[128 + ww];
        float mean = st * (1.f / 96.f);
        float var  = sst * (1.f / 96.f) - mean * mean;
        mr[ww] = mean; rs[ww] = rsqrtf(var + 1e-5f);
    }
    __syncthreads();
    float mean = mr[ww], rstd = rs[ww];

    int w = (bb << 8) + (hh >> 3) * 16 + (ww >> 3);
    int t = (w << 8) + d * 64 + (hh & 7) * 8 + (ww & 7);
    uint4* hq = (uint4*)(h + (long)t * 48 + half * 24);
    #pragma unroll
    for (int k = 0; k < 6; ++k) {
        int c = c0 + 8 * k;
        u32 q0 = pack2((xs[(c+0)*128+ww]-mean)*rstd*g1[c+0]+b1[c+0],
                       (xs[(c+1)*128+ww]-mean)*rstd*g1[c+1]+b1[c+1]);
        u32 q1 = pack2((xs[(c+2)*128+ww]-mean)*rstd*g1[c+2]+b1[c+2],
                       (xs[(c+3)*128+ww]-mean)*rstd*g1[c+3]+b1[c+3]);
        u32 q2 = pack2((xs[(c+4)*128+ww]-mean)*rstd*g1[c+4]+b1[c+4],
                       (xs[(c+5)*128+ww]-mean)*rstd*g1[c+5]+b1[c+5]);
        u32 q3 = pack2((xs[(c+6)*128+ww]-mean)*rstd*g1[c+6]+b1[c+6],
                       (xs[(c+7)*128+ww]-mean)*rstd*g1[c+7]+b1[c+7]);
        hq[k] = make_uint4(q0, q1, q2, q3);
    }
}

// ---------------- K2: QKV GEMM via MFMA [unchanged] ----------------
__global__ __launch_bounds__(256) void k_qkv_m(const __hip_bfloat16* __restrict__ h,
                                               const float* __restrict__ qkvw,
                                               const float* __restrict__ qkvb,
                                               __hip_bfloat16* __restrict__ qkv)
{
    __shared__ short wsm[288 * 96];
    int tid = threadIdx.x;
    for (int idx = tid; idx < 288 * 96; idx += 256) wsm[idx] = (short)bfbits(qkvw[idx]);
    __syncthreads();

    int wave = tid >> 6, lane = tid & 63;
    int quad = lane >> 4, l16 = lane & 15;
    int mbase = blockIdx.x * 256 + wave * 64;

    bf16x8 A[4][3];
    #pragma unroll
    for (int mm = 0; mm < 4; ++mm) {
        const __hip_bfloat16* ap = h + (long)(mbase + mm * 16 + l16) * 96 + quad * 8;
        A[mm][0] = *(const bf16x8*)(ap);
        A[mm][1] = *(const bf16x8*)(ap + 32);
        A[mm][2] = *(const bf16x8*)(ap + 64);
    }

    for (int nt = 0; nt < 18; ++nt) {
        int n0 = nt * 16;
        const short* bp = &wsm[(n0 + l16) * 96 + quad * 8];
        bf16x8 B0 = *(const bf16x8*)(bp);
        bf16x8 B1 = *(const bf16x8*)(bp + 32);
        bf16x8 B2 = *(const bf16x8*)(bp + 64);
        int r    = n0 + l16;
        int type = n0 / 96;
        int head = (n0 % 96) / 32;
        int dd   = r & 31;
        float bias = qkvb[r];
        float scl  = (type == 0) ? 0.17677669529663687f : 1.0f;
        long tbase = (long)type * QKV_STRIDE;
        #pragma unroll
        for (int mm = 0; mm < 4; ++mm) {
            f32x4 acc = {0.f, 0.f, 0.f, 0.f};
            acc = MFMA(A[mm][0], B0, acc);
            acc = MFMA(A[mm][1], B1, acc);
            acc = MFMA(A[mm][2], B2, acc);
            int tok0 = mbase + mm * 16 + quad * 4;
            int w = tok0 >> 8, nn = tok0 & 255;
            long dst0 = tbase + (long)(w * 3 + head) * 8192 + nn * 32 + dd;
            #pragma unroll
            for (int rg = 0; rg < 4; ++rg)
                qkv[dst0 + (long)rg * 32] = __float2bfloat16((acc[rg] + bias) * scl);
        }
    }
}

// ---------------- K3: window attention via MFMA (transposed bias table) ----------------
__global__ __launch_bounds__(256) void k_attn_m(const __hip_bfloat16* __restrict__ qkv,
                                                const float* __restrict__ btab,
                                                __hip_bfloat16* __restrict__ o)
{
    __shared__ short vt[32 * 264];        // V^T [d][key], pitch 264 (b128-aligned)
    __shared__ short pm[4 * 16 * 264];    // per-wave P [query16][key256 pad]
    __shared__ float bsT[31 * 33];        // bias transposed: bsT[c2][r2], odd pitch
    int wh = blockIdx.x, head = wh % 3, w = wh / 3;
    int tid = threadIdx.x;

    const u32* vg = (const u32*)(qkv + 2u * QKV_STRIDE + (long)wh * 8192);
    for (int idx = tid; idx < 4096; idx += 256) {
        u32 pv = vg[idx];
        int kr = idx >> 4, d0 = (idx & 15) * 2;
        vt[d0 * 264 + kr]       = (short)(pv & 0xffffu);
        vt[(d0 + 1) * 264 + kr] = (short)(pv >> 16);
    }
    for (int idx = tid; idx < 961; idx += 256) {
        int c2 = idx / 31, r2 = idx - c2 * 31;
        bsT[c2 * 33 + r2] = btab[(r2 * 31 + c2) * 3 + head];
    }
    __syncthreads();

    int wave = tid >> 6, lane = tid & 63, quad = lane >> 4, l16 = lane & 15;
    const __hip_bfloat16* qb = qkv + (long)wh * 8192;
    const __hip_bfloat16* kb = qkv + QKV_STRIDE + (long)wh * 8192;
    short* pmw = &pm[wave * 16 * 264];

    bf16x8 kf[16];
    #pragma unroll
    for (int kt = 0; kt < 16; ++kt)
        kf[kt] = *(const bf16x8*)(kb + (kt * 16 + l16) * 32 + quad * 8);

    for (int g = 0; g < 4; ++g) {
        int qg = wave * 4 + g;
        bf16x8 qf = *(const bf16x8*)(qb + (qg * 16 + l16) * 32 + quad * 8);
        f32x4 s[16];
        #pragma unroll
        for (int kt = 0; kt < 16; ++kt) {
            f32x4 z = {0.f, 0.f, 0.f, 0.f};
            s[kt] = MFMA(kf[kt], qf, z);
        }
        // bias: for each rg, the 16 kt-values are CONSECUTIVE floats in bsT
        #pragma unroll
        for (int rg = 0; rg < 4; ++rg) {
            const float* bp2 = &bsT[(l16 - quad * 4 + 15 - rg) * 33 + qg + 15];
            #pragma unroll
            for (int kt = 0; kt < 16; ++kt)
                s[kt][rg] += bp2[-kt];
        }
        float mx = -1e30f;
        #pragma unroll
        for (int kt = 0; kt < 16; ++kt)
            #pragma unroll
            for (int rg = 0; rg < 4; ++rg) mx = fmaxf(mx, s[kt][rg]);
        mx = fmaxf(mx, __shfl_xor(mx, 16));
        mx = fmaxf(mx, __shfl_xor(mx, 32));
        float lsum = 0.f;
        #pragma unroll
        for (int kt = 0; kt < 16; ++kt)
            #pragma unroll
            for (int rg = 0; rg < 4; ++rg) {
                float p = __expf(s[kt][rg] - mx);
                s[kt][rg] = p; lsum += p;
            }
        lsum += __shfl_xor(lsum, 16);
        lsum += __shfl_xor(lsum, 32);
        float inv = 1.f / lsum;
        #pragma unroll
        for (int kt = 0; kt < 16; ++kt)
            #pragma unroll
            for (int rg = 0; rg < 4; ++rg)
                pmw[l16 * 264 + kt * 16 + quad * 4 + rg] = (short)bfbits(s[kt][rg] * inv);
        f32x4 a0 = {0.f, 0.f, 0.f, 0.f}, a1 = {0.f, 0.f, 0.f, 0.f};
        #pragma unroll
        for (int k2 = 0; k2 < 8; ++k2) {
            bf16x8 pf = *(const bf16x8*)&pmw[l16 * 264 + k2 * 32 + quad * 8];
            bf16x8 v0 = *(const bf16x8*)&vt[l16 * 264 + k2 * 32 + quad * 8];
            bf16x8 v1 = *(const bf16x8*)&vt[(16 + l16) * 264 + k2 * 32 + quad * 8];
            a0 = MFMA(pf, v0, a0);
            a1 = MFMA(pf, v1, a1);
        }
        #pragma unroll
        for (int rg = 0; rg < 4; ++rg) {
            int qrow = qg * 16 + quad * 4 + rg;
            __hip_bfloat16* op = o + (long)(w * 256 + qrow) * 96 + head * 32;
            op[l16]      = __float2bfloat16(a0[rg]);
            op[16 + l16] = __float2bfloat16(a1[rg]);
        }
    }
}

// ---------------- K4a: proj (no residual) -> pbuf (bf16), MFMA [unchanged] ----------------
__global__ __launch_bounds__(256) void k_proj_nr(const __hip_bfloat16* __restrict__ o,
                                                 const float* __restrict__ pw,
                                                 const float* __restrict__ pb,
                                                 __hip_bfloat16* __restrict__ pbuf)
{
    __shared__ short wsm[96 * 96];
    int tid = threadIdx.x;
    for (int idx = tid; idx < 96 * 96; idx += 256) wsm[idx] = (short)bfbits(pw[idx]);
    __syncthreads();

    int wave = tid >> 6, lane = tid & 63;
    int quad = lane >> 4, l16 = lane & 15;
    int mbase = blockIdx.x * 256 + wave * 64;

    bf16x8 A[4][3];
    #pragma unroll
    for (int mm = 0; mm < 4; ++mm) {
        const __hip_bfloat16* ap = o + (long)(mbase + mm * 16 + l16) * 96 + quad * 8;
        A[mm][0] = *(const bf16x8*)(ap);
        A[mm][1] = *(const bf16x8*)(ap + 32);
        A[mm][2] = *(const bf16x8*)(ap + 64);
    }

    for (int nt = 0; nt < 6; ++nt) {
        int n0 = nt * 16;
        const short* bp = &wsm[(n0 + l16) * 96 + quad * 8];
        bf16x8 B0 = *(const bf16x8*)(bp);
        bf16x8 B1 = *(const bf16x8*)(bp + 32);
        bf16x8 B2 = *(const bf16x8*)(bp + 64);
        int c = n0 + l16;
        float bias = pb[c];
        #pragma unroll
        for (int mm = 0; mm < 4; ++mm) {
            f32x4 acc = {0.f, 0.f, 0.f, 0.f};
            acc = MFMA(A[mm][0], B0, acc);
            acc = MFMA(A[mm][1], B1, acc);
            acc = MFMA(A[mm][2], B2, acc);
            int tok0 = mbase + mm * 16 + quad * 4;
            #pragma unroll
            for (int rg = 0; rg < 4; ++rg)
                pbuf[(long)(tok0 + rg) * 96 + c] = __float2bfloat16(acc[rg] + bias);
        }
    }
}

// ---------------- K4b: residual + LN2 -> t2 (bf16), h2 (bf16) ----------------
__global__ __launch_bounds__(256) void k_addln2(const float* __restrict__ x,
                                                const __hip_bfloat16* __restrict__ pbuf,
                                                const float* __restrict__ g2,
                                                const float* __restrict__ b2,
                                                u32* __restrict__ t2,
                                                u32* __restrict__ h2)
{
    __shared__ float xs[96 * 128];
    __shared__ float ps[256], pss[256], mr[128], rs[128];
    int blk = blockIdx.x;
    int hh = blk & 127, d = (blk >> 7) & 3, bb = blk >> 9;
    long base = (long)bb * 6291456 + (long)d * 16384 + hh * 128;
    for (int i = threadIdx.x; i < 3072; i += 256) {
        int c = i >> 5, w4 = i & 31;
        ((float4*)xs)[i] = *(const float4*)(x + base + (long)c * 65536 + w4 * 4);
    }
    __syncthreads();

    int tid = threadIdx.x, half = tid >> 7, ww = tid & 127;
    int c0 = half * 48;
    int w = (bb << 8) + (hh >> 3) * 16 + (ww >> 3);
    int t = (w << 8) + d * 64 + (hh & 7) * 8 + (ww & 7);

    const u32* pr = (const u32*)pbuf + (long)t * 48 + half * 24;
    float pv[48];
    float s = 0.f, ssq = 0.f;
    #pragma unroll
    for (int k = 0; k < 24; ++k) {
        u32 u = pr[k];
        float v0 = bl(u) + xs[(c0 + 2 * k) * 128 + ww];
        float v1 = bh(u) + xs[(c0 + 2 * k + 1) * 128 + ww];
        pv[2 * k] = v0; pv[2 * k + 1] = v1;
        s += v0 + v1; ssq += v0 * v0 + v1 * v1;
    }
    ps[tid] = s; pss[tid] = ssq;
    __syncthreads();
    if (half == 0) {
        float st = ps[ww] + ps[128 + ww], sst = pss[ww] + pss[128 + ww];
        float mean = st * (1.f / 96.f);
        float var  = sst * (1.f / 96.f) - mean * mean;
        mr[ww] = mean; rs[ww] = rsqrtf(var + 1e-5f);
    }
    __syncthreads();
    float mean = mr[ww], rstd = rs[ww];

    uint4* t2q = (uint4*)(t2 + (long)t * 48 + half * 24);
    uint4* hq  = (uint4*)(h2 + (long)t * 48 + half * 24);
    #pragma unroll
    for (int k = 0; k < 6; ++k) {
        int c = c0 + 8 * k;
        u32 t0v = pack2(pv[8*k+0], pv[8*k+1]);
        u32 t1v = pack2(pv[8*k+2], pv[8*k+3]);
        u32 t2v = pack2(pv[8*k+4], pv[8*k+5]);
        u32 t3v = pack2(pv[8*k+6], pv[8*k+7]);
        t2q[k] = make_uint4(t0v, t1v, t2v, t3v);
        u32 q0 = pack2((pv[8*k+0]-mean)*rstd*g2[c+0]+b2[c+0],
                       (pv[8*k+1]-mean)*rstd*g2[c+1]+b2[c+1]);
        u32 q1 = pack2((pv[8*k+2]-mean)*rstd*g2[c+2]+b2[c+2],
                       (pv[8*k+3]-mean)*rstd*g2[c+3]+b2[c+3]);
        u32 q2 = pack2((pv[8*k+4]-mean)*rstd*g2[c+4]+b2[c+4],
                       (pv[8*k+5]-mean)*rstd*g2[c+5]+b2[c+5]);
        u32 q3 = pack2((pv[8*k+6]-mean)*rstd*g2[c+6]+b2[c+6],
                       (pv[8*k+7]-mean)*rstd*g2[c+7]+b2[c+7]);
        hq[k] = make_uint4(q0, q1, q2, q3);
    }
}

// ---------------- K5: fc1 + exact GELU via MFMA [unchanged logic] ----------------
__global__ __launch_bounds__(256) void k_fc1_m(const __hip_bfloat16* __restrict__ h2,
                                               const float* __restrict__ fw,
                                               const float* __restrict__ fb,
                                               __hip_bfloat16* __restrict__ m1, int t0)
{
    __shared__ short wsm[192 * 96];
    int tid = threadIdx.x;
    int wave = tid >> 6, lane = tid & 63;
    int quad = lane >> 4, l16 = lane & 15;
    int mbaseL = blockIdx.x * 128 + wave * 32;

    bf16x8 A[2][3];
    #pragma unroll
    for (int mm = 0; mm < 2; ++mm) {
        const __hip_bfloat16* ap = h2 + (long)(t0 + mbaseL + mm * 16 + l16) * 96 + quad * 8;
        A[mm][0] = *(const bf16x8*)(ap);
        A[mm][1] = *(const bf16x8*)(ap + 32);
        A[mm][2] = *(const bf16x8*)(ap + 64);
    }

    const float is2 = 0.70710678118654752440f;
    for (int ph = 0; ph < 2; ++ph) {
        if (ph) __syncthreads();
        for (int idx = tid; idx < 192 * 96; idx += 256)
            wsm[idx] = (short)bfbits(fw[ph * 192 * 96 + idx]);
        __syncthreads();
        for (int nt = 0; nt < 12; ++nt) {
            int n0 = nt * 16;
            const short* bp = &wsm[(n0 + l16) * 96 + quad * 8];
            bf16x8 B0 = *(const bf16x8*)(bp);
            bf16x8 B1 = *(const bf16x8*)(bp + 32);
            bf16x8 B2 = *(const bf16x8*)(bp + 64);
            int r = ph * 192 + n0 + l16;
            float bias = fb[r];
            #pragma unroll
            for (int mm = 0; mm < 2; ++mm) {
                f32x4 acc = {0.f, 0.f, 0.f, 0.f};
                acc = MFMA(A[mm][0], B0, acc);
                acc = MFMA(A[mm][1], B1, acc);
                acc = MFMA(A[mm][2], B2, acc);
                int tokL0 = mbaseL + mm * 16 + quad * 4;
                #pragma unroll
                for (int rg = 0; rg < 4; ++rg) {
                    float v = acc[rg] + bias;
                    v = 0.5f * v * (1.f + erff(v * is2));
                    m1[(long)(tokL0 + rg) * 384 + r] = __float2bfloat16(v);
                }
            }
        }
    }
}

// ---------------- K6: fc2 + residual(t2 bf16) -> out via MFMA ----------------
__global__ __launch_bounds__(256) void k_fc2_m(const __hip_bfloat16* __restrict__ m1,
                                               const float* __restrict__ fw,
                                               const float* __restrict__ fb,
                                               const __hip_bfloat16* __restrict__ t2,
                                               float* __restrict__ out, int t0)
{
    __shared__ short wsm[48 * 392];
    int tid = threadIdx.x;
    int wave = tid >> 6, lane = tid & 63;
    int quad = lane >> 4, l16 = lane & 15;
    int mbaseL = blockIdx.x * 128 + wave * 32;

    bf16x8 A[2][12];
    #pragma unroll
    for (int mm = 0; mm < 2; ++mm) {
        const __hip_bfloat16* ap = m1 + (long)(mbaseL + mm * 16 + l16) * 384 + quad * 8;
        #pragma unroll
        for (int kc = 0; kc < 12; ++kc)
            A[mm][kc] = *(const bf16x8*)(ap + kc * 32);
    }

    for (int ph = 0; ph < 2; ++ph) {
        if (ph) __syncthreads();
        for (int idx = tid; idx < 48 * 384; idx += 256) {
            int rr = idx / 384, cc = idx - rr * 384;
            wsm[rr * 392 + cc] = (short)bfbits(fw[(ph * 48 + rr) * 384 + cc]);
        }
        __syncthreads();
        for (int nt = 0; nt < 3; ++nt) {
            int n0 = nt * 16;
            const short* bp = &wsm[(n0 + l16) * 392 + quad * 8];
            bf16x8 B[12];
            #pragma unroll
            for (int kc = 0; kc < 12; ++kc)
                B[kc] = *(const bf16x8*)(bp + kc * 32);
            int c = ph * 48 + n0 + l16;
            float bias = fb[c];
            #pragma unroll
            for (int mm = 0; mm < 2; ++mm) {
                f32x4 acc = {0.f, 0.f, 0.f, 0.f};
                #pragma unroll
                for (int kc = 0; kc < 12; ++kc)
                    acc = MFMA(A[mm][kc], B[kc], acc);
                int tok0 = t0 + mbaseL + mm * 16 + quad * 4;
                #pragma unroll
                for (int rg = 0; rg < 4; ++rg) {
                    long g = (long)(tok0 + rg) * 96 + c;
                    out[g] = __bfloat162float(t2[g]) + acc[rg] + bias;
                }
            }
        }
    }
}

extern "C" void kernel_launch(void* const* d_in, const int* in_sizes, int n_in,
                              void* d_out, int out_size, void* d_ws, size_t ws_size,
                              hipStream_t stream)
{
    const float* x     = (const float*)d_in[0];
    const float* qkvw  = (const float*)d_in[1];
    const float* qkvb  = (const float*)d_in[2];
    const float* projw = (const float*)d_in[3];
    const float* projb = (const float*)d_in[4];
    const float* btab  = (const float*)d_in[5];
    const float* ln1g  = (const float*)d_in[6];
    const float* ln1b  = (const float*)d_in[7];
    const float* ln2g  = (const float*)d_in[8];
    const float* ln2b  = (const float*)d_in[9];
    const float* fc1w  = (const float*)d_in[10];
    const float* fc1b  = (const float*)d_in[11];
    const float* fc2w  = (const float*)d_in[12];
    const float* fc2b  = (const float*)d_in[13];
    float* out = (float*)d_out;

    if (ws_size < WS_NEED) {
        k_fill<<<49152, 256, 0, stream>>>(out, out_size);
        return;
    }

    // ws lifetimes (96 MiB):
    //  [0,72)  : qkv(bf16) -> { pbuf bf16 [0,24) -> m1 chunk bf16 [0,48) ; t2 bf16 [48,72) }
    //  [72,96) : h(bf16) -> o(bf16) -> h2(bf16)
    char* ws = (char*)d_ws;
    __hip_bfloat16* qkvB  = (__hip_bfloat16*)(ws);
    __hip_bfloat16* pbuf  = (__hip_bfloat16*)(ws);
    __hip_bfloat16* m1buf = (__hip_bfloat16*)(ws);
    __hip_bfloat16* t2buf = (__hip_bfloat16*)(ws + 50331648);
    __hip_bfloat16* hbuf  = (__hip_bfloat16*)(ws + 75497472);
    __hip_bfloat16* obuf  = hbuf;
    __hip_bfloat16* h2buf = hbuf;

    k_ln1_c <<<1024, 256, 0, stream>>>(x, ln1g, ln1b, (u32*)hbuf);
    k_qkv_m <<<512,  256, 0, stream>>>(hbuf, qkvw, qkvb, qkvB);
    k_attn_m<<<1536, 256, 0, stream>>>(qkvB, btab, obuf);
    k_proj_nr<<<512, 256, 0, stream>>>(obuf, projw, projb, pbuf);
    k_addln2<<<1024, 256, 0, stream>>>(x, pbuf, ln2g, ln2b, (u32*)t2buf, (u32*)h2buf);
    for (int ch = 0; ch < 2; ++ch) {
        int t0 = ch * 65536;
        k_fc1_m<<<512, 256, 0, stream>>>(h2buf, fc1w, fc1b, m1buf, t0);
        k_fc2_m<<<512, 256, 0, stream>>>(m1buf, fc2w, fc2b, t2buf, out, t0);
    }
}